// Round 12
// baseline (1929.888 us; speedup 1.0000x reference)
//
#include <hip/hip_runtime.h>
#include <math.h>

// ---- problem constants ----
#define C_      3
#define H_      224
#define W_      224
#define KH_     14
#define KW_     14
#define NPATCH  196
#define PELEMS  768
#define D_      768
#define HEADS_  12
#define Y_      64
#define MHID    3072
#define NMASK   100
#define NSTEPS  12
#define ALPHA_  0.1f
#define BETA_   0.125f
#define EPS_    1e-5f
#define B_      16
#define NTOK    197
#define ROWS    (B_*NTOK)   /* 3152 real rows */
#define MPAD    3200        /* 50 * 64 */
#define QKLD    1536        /* fused q|k leading dim */
#define PACKLD  4608        /* hid(3072) | Gq(768) | Gk(768) */
#define W2LD    4608        /* qk(1536) | hid(3072) fused B rows */
#define KSPLIT  4           /* grad GEMM split-K (4608/4=1152=18*64).
                               R8-proven: partial-store + fused reduce, 55.4us. */

typedef short short8 __attribute__((ext_vector_type(8)));
typedef unsigned short ushort8 __attribute__((ext_vector_type(8)));
typedef float floatx4 __attribute__((ext_vector_type(4)));

__device__ __forceinline__ unsigned short f2bf(float f) {
    union { float f; unsigned u; } v; v.f = f;
    unsigned r = (v.u + 0x7FFFu + ((v.u >> 16) & 1u)) >> 16;
    return (unsigned short)r;
}
__device__ __forceinline__ float bf2f(unsigned short u) {
    union { unsigned u; float f; } v; v.u = ((unsigned)u) << 16;
    return v.f;
}

__device__ __forceinline__ void async_cp16(const void* g, void* l) {
    __builtin_amdgcn_global_load_lds(
        (const __attribute__((address_space(1))) unsigned int*)g,
        (__attribute__((address_space(3))) unsigned int*)l, 16, 0, 0);
}

// ---------------------------------------------------------------------------
// MFMA bf16 NT GEMM: C[M][N] = A(MxK bf16) @ B(NxK bf16)^T.
// 64x128 tile, BK=64/iter, single-buffer 2-barrier loop (R2-proven; explicit
// dbuf measured WORSE — R7: occupancy 35->25%).
// R11: SWZ template flag. R10 measured the XCD swizzle helps the wide fwd
// GEMM (mode-3) but REGRESSES the latency-bound split-K grad GEMM
// (mode-5: 55.4 -> 63 us despite FETCH 104 -> 86 MB) — packing same-panel
// blocks on one XCD serializes L2 access instead of spreading MLP.
// OUT_MODE: 0 = fp32 store, 1 = bf16 store,
//           3 = split epilogue: col<1536 -> Cout bf16 (ld QKLD), else relu ->
//               Cout2 bf16 (ld PACKLD, col-1536)
//           5 = split-K partial: koff = bz*K, plain fp32 store to
//               Cout + bz*MPAD*D_ (no atomics; reduced in upd_lnorm_kernel)
template<int OUT_MODE, bool RELU, bool HAS_BIAS, bool SWZ>
__global__ __launch_bounds__(256) void mfma_gemm(
    const unsigned short* __restrict__ A, int lda,
    const unsigned short* __restrict__ B, int ldb,
    void* __restrict__ Cout, int ldc, void* __restrict__ Cout2,
    const float* __restrict__ bias, int K)
{
    __shared__ alignas(16) unsigned short ldsA[2][64 * 32];
    __shared__ alignas(16) unsigned short ldsB[2][128 * 32];

    int bx, by, bz;
    if (SWZ) {
        // XCD-aware bijective swizzle (handles nwg%8 != 0)
        const int gx = gridDim.x, gy = gridDim.y;
        const int nwg = gx * gy * gridDim.z;
        const int orig = blockIdx.x + gx * (blockIdx.y + gy * blockIdx.z);
        const int xcd = orig & 7, q = nwg >> 3, rr8 = nwg & 7;
        const int s = ((xcd < rr8) ? xcd * (q + 1) : rr8 * (q + 1) + (xcd - rr8) * q)
                      + (orig >> 3);
        bx = s % gx;
        by = (s / gx) % gy;
        bz = s / (gx * gy);
    } else {
        bx = blockIdx.x; by = blockIdx.y; bz = blockIdx.z;
    }

    const int koff = (OUT_MODE == 5) ? bz * K : 0;

    const int t    = threadIdx.x;
    const int wave = t >> 6;
    const int lane = t & 63;
    const int row0 = by << 6;
    const int col0 = bx << 7;
    const int wm = (wave & 1) << 5;
    const int wn = (wave >> 1) << 6;
    const int r  = lane & 15;
    const int qd = lane >> 4;

    const unsigned short* Abase = A + (size_t)row0 * lda + koff;
    const unsigned short* Bbase = B + (size_t)col0 * ldb + koff;

    floatx4 acc[2][4];
#pragma unroll
    for (int i = 0; i < 2; ++i)
#pragma unroll
        for (int j = 0; j < 4; ++j)
            acc[i][j] = (floatx4){0.f, 0.f, 0.f, 0.f};

    const int crow = t >> 2;
    const int coff = (t & 3) << 3;
    for (int k0 = 0; k0 < K; k0 += 64) {
#pragma unroll
        for (int kb = 0; kb < 2; ++kb) {
            const int kk = k0 + kb * 32;
            async_cp16(Abase + (size_t)crow * lda + kk + coff,
                       ldsA[kb] + (wave << 9));
            async_cp16(Bbase + (size_t)crow * ldb + kk + coff,
                       ldsB[kb] + (wave << 9));
            async_cp16(Bbase + (size_t)(64 + crow) * ldb + kk + coff,
                       ldsB[kb] + 2048 + (wave << 9));
        }
        __syncthreads();
#pragma unroll
        for (int kb = 0; kb < 2; ++kb) {
            short8 af[2], bfr[4];
#pragma unroll
            for (int i = 0; i < 2; ++i)
                af[i]  = *(const short8*)&ldsA[kb][(wm + (i << 4) + r) * 32 + (qd << 3)];
#pragma unroll
            for (int j = 0; j < 4; ++j)
                bfr[j] = *(const short8*)&ldsB[kb][(wn + (j << 4) + r) * 32 + (qd << 3)];
#pragma unroll
            for (int i = 0; i < 2; ++i)
#pragma unroll
                for (int j = 0; j < 4; ++j)
                    acc[i][j] = __builtin_amdgcn_mfma_f32_16x16x32_bf16(
                                    af[i], bfr[j], acc[i][j], 0, 0, 0);
        }
        __syncthreads();
    }

    float* Cpart = (OUT_MODE == 5)
        ? (float*)Cout + (size_t)bz * ((size_t)MPAD * D_) : (float*)Cout;

#pragma unroll
    for (int i = 0; i < 2; ++i) {
#pragma unroll
        for (int j = 0; j < 4; ++j) {
            int cc = col0 + wn + (j << 4) + r;
#pragma unroll
            for (int reg = 0; reg < 4; ++reg) {
                int rr = row0 + wm + (i << 4) + (qd << 2) + reg;
                float v = acc[i][j][reg];
                if (HAS_BIAS) v += bias[cc];
                if (RELU)     v = fmaxf(v, 0.f);
                if (OUT_MODE == 1)
                    ((unsigned short*)Cout)[(size_t)rr * ldc + cc] = f2bf(v);
                else if (OUT_MODE == 3) {
                    if (cc < QKLD)
                        ((unsigned short*)Cout)[(size_t)rr * QKLD + cc] = f2bf(v);
                    else
                        ((unsigned short*)Cout2)[(size_t)rr * PACKLD + (cc - QKLD)]
                            = f2bf(fmaxf(v, 0.f));
                } else if (OUT_MODE == 5)
                    Cpart[(size_t)rr * ldc + cc] = v;
                else
                    ((float*)Cout)[(size_t)rr * ldc + cc] = v;
            }
        }
    }
}

// ---------------------------------------------------------------------------
// Fused attention: replaces tqk + attn_pgq + attn_pv.
// One block per (b,h): grid 192, 512 threads (8 waves), 128,000 B LDS.
//   Ks  [208][72]  bf16  K_h m-major (m>=197 zero)          29,952 B
//   Kt  [64][232]  bf16  K_h y-major (m-cols 197..223 zero) 29,696 B
//   Qc  [32][72]   bf16  Q n-chunk (rows>=csz zero)          4,608 B
//   Qtc [64][40]   bf16  Q-chunk y-major (n-cols>=csz zero)  5,120 B
//   Pb  [32][232]  bf16  P chunk n-major (cols>=197 zero)   14,848 B
//   PTb [208][40]  bf16  P chunk m-major                    16,640 B
//   Pm  [32][212]  fp32  S / softmax scratch                27,136 B
// Per chunk: S = Qc @ Ks^T (MFMA) -> softmax (beta in exp, m>=NTOK masked)
// -> Pb/PTb -> Gq = Pb @ Kt^T stored to pack[3072..], Gk += PTb @ Qtc^T
// accumulated in registers (7 statically-indexed floatx4), stored at end to
// pack[3840..]. P/PT/kT/qT never touch global memory.
__global__ __launch_bounds__(512) void attn_fused_kernel(
    const unsigned short* __restrict__ qk,   // bf16 [MPAD][1536]
    unsigned short* __restrict__ pack)       // bf16 [MPAD][4608]
{
    __shared__ alignas(16) unsigned short Ks[208 * 72];
    __shared__ alignas(16) unsigned short Kt[64 * 232];
    __shared__ alignas(16) unsigned short Qc[32 * 72];
    __shared__ alignas(16) unsigned short Qtc[64 * 40];
    __shared__ alignas(16) unsigned short Pb[32 * 232];
    __shared__ alignas(16) unsigned short PTb[208 * 40];
    __shared__ alignas(16) float Pm[32 * 212];

    const int bh = blockIdx.x;
    const int h = bh % HEADS_, b = bh / HEADS_;
    const int t = threadIdx.x;
    const int lane = t & 63, wave = t >> 6;
    const int ln15 = lane & 15, quad = lane >> 4;
    const size_t rowbase = (size_t)(b * NTOK) * QKLD;
    const int hoff = h * 64;

    // ---- phase 0: load K_h (zero-padded to 208 rows), zero Pb/PTb ----
    for (int idx = t; idx < 208 * 8; idx += 512) {
        int m = idx >> 3, c8 = idx & 7;
        uint4 v = (uint4){0, 0, 0, 0};
        if (m < NTOK)
            v = *(const uint4*)&qk[rowbase + (size_t)m * QKLD + 768 + hoff + c8 * 8];
        *(uint4*)&Ks[m * 72 + c8 * 8] = v;
    }
    for (int idx = t; idx < (32 * 232) / 8; idx += 512)
        *(uint4*)&Pb[idx * 8] = (uint4){0, 0, 0, 0};
    for (int idx = t; idx < (208 * 40) / 8; idx += 512)
        *(uint4*)&PTb[idx * 8] = (uint4){0, 0, 0, 0};
    __syncthreads();

    // ---- build Kt[y][m] = Ks[m][y]  (m 0..223, zeros past 207) ----
    for (int idx = t; idx < 64 * 112; idx += 512) {
        int y = idx / 112, mp = idx % 112;
        int m0 = 2 * mp;
        unsigned lo = (m0     < 208) ? Ks[(m0    ) * 72 + y] : 0u;
        unsigned hi = (m0 + 1 < 208) ? Ks[(m0 + 1) * 72 + y] : 0u;
        *(unsigned*)&Kt[y * 232 + m0] = lo | (hi << 16);
    }
    __syncthreads();

    // ---- Gk accumulators: 52 (mt,yt) tiles over 8 waves, static index ----
    floatx4 gk[7];
#pragma unroll
    for (int i = 0; i < 7; ++i) gk[i] = (floatx4){0.f, 0.f, 0.f, 0.f};

    for (int nc = 0; nc < 7; ++nc) {
        const int n0 = nc * 32;
        const int csz = (NTOK - n0 < 32) ? (NTOK - n0) : 32;

        // -- load Q chunk (rows >= csz zeroed) --
        for (int idx = t; idx < 32 * 8; idx += 512) {
            int nn = idx >> 3, c8 = idx & 7;
            uint4 v = (uint4){0, 0, 0, 0};
            if (nn < csz)
                v = *(const uint4*)&qk[rowbase + (size_t)(n0 + nn) * QKLD + hoff + c8 * 8];
            *(uint4*)&Qc[nn * 72 + c8 * 8] = v;
        }
        __syncthreads();   // bar1: Qc ready; prev-iter Gq/Gk done (Qtc safe)

        // -- build Qtc[y][nn] = Qc[nn][y]  (cols >= csz zero via Qc pad) --
        for (int idx = t; idx < 64 * 16; idx += 512) {
            int y = idx >> 4, np = idx & 15;
            unsigned lo = Qc[(2 * np    ) * 72 + y];
            unsigned hi = Qc[(2 * np + 1) * 72 + y];
            *(unsigned*)&Qtc[y * 40 + 2 * np] = lo | (hi << 16);
        }

        // -- S = Qc @ Ks^T  (waves split the 13 m-tiles) --
        {
            short8 aq[2][2];
#pragma unroll
            for (int nt = 0; nt < 2; ++nt)
#pragma unroll
                for (int kb = 0; kb < 2; ++kb)
                    aq[nt][kb] = *(const short8*)
                        &Qc[(nt * 16 + ln15) * 72 + kb * 32 + quad * 8];

            for (int mt = wave; mt < 13; mt += 8) {
                short8 b0 = *(const short8*)&Ks[(mt * 16 + ln15) * 72 + quad * 8];
                short8 b1 = *(const short8*)&Ks[(mt * 16 + ln15) * 72 + 32 + quad * 8];
                floatx4 s0 = (floatx4){0.f, 0.f, 0.f, 0.f};
                floatx4 s1 = (floatx4){0.f, 0.f, 0.f, 0.f};
                s0 = __builtin_amdgcn_mfma_f32_16x16x32_bf16(aq[0][0], b0, s0, 0, 0, 0);
                s0 = __builtin_amdgcn_mfma_f32_16x16x32_bf16(aq[0][1], b1, s0, 0, 0, 0);
                s1 = __builtin_amdgcn_mfma_f32_16x16x32_bf16(aq[1][0], b0, s1, 0, 0, 0);
                s1 = __builtin_amdgcn_mfma_f32_16x16x32_bf16(aq[1][1], b1, s1, 0, 0, 0);
#pragma unroll
                for (int reg = 0; reg < 4; ++reg) {
                    Pm[(quad * 4 + reg) * 212 + mt * 16 + ln15]      = s0[reg];
                    Pm[(16 + quad * 4 + reg) * 212 + mt * 16 + ln15] = s1[reg];
                }
            }
        }
        __syncthreads();   // bar2: Pm ready

        // -- softmax rows (beta inside exp); emit Pb (n-major) + PTb (m-major)
        for (int nn = wave; nn < csz; nn += 8) {
            float v0 = Pm[nn * 212 + lane];
            float v1 = (lane +  64 < NTOK) ? Pm[nn * 212 + lane +  64] : -1e30f;
            float v2 = (lane + 128 < NTOK) ? Pm[nn * 212 + lane + 128] : -1e30f;
            float v3 = (lane + 192 < NTOK) ? Pm[nn * 212 + lane + 192] : -1e30f;
            float mx = fmaxf(fmaxf(v0, v1), fmaxf(v2, v3));
#pragma unroll
            for (int o = 32; o > 0; o >>= 1) mx = fmaxf(mx, __shfl_xor(mx, o, 64));
            float e0 = __expf((v0 - mx) * BETA_);
            float e1 = (lane +  64 < NTOK) ? __expf((v1 - mx) * BETA_) : 0.f;
            float e2 = (lane + 128 < NTOK) ? __expf((v2 - mx) * BETA_) : 0.f;
            float e3 = (lane + 192 < NTOK) ? __expf((v3 - mx) * BETA_) : 0.f;
            float s = e0 + e1 + e2 + e3;
#pragma unroll
            for (int o = 32; o > 0; o >>= 1) s += __shfl_xor(s, o, 64);
            float inv = 1.0f / s;
            {
                unsigned short p = f2bf(e0 * inv);
                Pb[nn * 232 + lane] = p;
                PTb[lane * 40 + nn] = p;
            }
            {
                unsigned short p = f2bf(e1 * inv);
                Pb[nn * 232 + lane + 64] = p;
                PTb[(lane + 64) * 40 + nn] = p;
            }
            {
                unsigned short p = f2bf(e2 * inv);
                Pb[nn * 232 + lane + 128] = p;
                PTb[(lane + 128) * 40 + nn] = p;
            }
            if (lane + 192 < NTOK) {
                unsigned short p = f2bf(e3 * inv);
                Pb[nn * 232 + lane + 192] = p;
                PTb[(lane + 192) * 40 + nn] = p;
            }
        }
        __syncthreads();   // bar3: Pb/PTb ready

        // -- Gq = Pb @ Kt^T : 8 output tiles, one per wave; store to pack --
        {
            const int nt = wave >> 2, yt = wave & 3;
            floatx4 gq = (floatx4){0.f, 0.f, 0.f, 0.f};
#pragma unroll
            for (int ks = 0; ks < 7; ++ks) {
                short8 a  = *(const short8*)&Pb[(nt * 16 + ln15) * 232 + ks * 32 + quad * 8];
                short8 bk = *(const short8*)&Kt[(yt * 16 + ln15) * 232 + ks * 32 + quad * 8];
                gq = __builtin_amdgcn_mfma_f32_16x16x32_bf16(a, bk, gq, 0, 0, 0);
            }
#pragma unroll
            for (int reg = 0; reg < 4; ++reg) {
                int row = nt * 16 + quad * 4 + reg;
                if (row < csz)
                    pack[(size_t)(b * NTOK + n0 + row) * PACKLD
                         + 3072 + hoff + yt * 16 + ln15] = f2bf(gq[reg]);
            }
        }

        // -- Gk += PTb @ Qtc^T : 52 tiles over 8 waves (static acc index) --
#pragma unroll
        for (int i = 0; i < 7; ++i) {
            int ti = wave + i * 8;
            if (ti < 52) {
                int mt = ti >> 2, yt = ti & 3;
                short8 a  = *(const short8*)&PTb[(mt * 16 + ln15) * 40 + quad * 8];
                short8 bq = *(const short8*)&Qtc[(yt * 16 + ln15) * 40 + quad * 8];
                gk[i] = __builtin_amdgcn_mfma_f32_16x16x32_bf16(a, bq, gk[i], 0, 0, 0);
            }
        }
    }

    // ---- store Gk ----
#pragma unroll
    for (int i = 0; i < 7; ++i) {
        int ti = wave + i * 8;
        if (ti < 52) {
            int mt = ti >> 2, yt = ti & 3;
#pragma unroll
            for (int reg = 0; reg < 4; ++reg) {
                int m = mt * 16 + quad * 4 + reg;
                if (m < NTOK)
                    pack[(size_t)(b * NTOK + m) * PACKLD
                         + 3840 + hoff + yt * 16 + ln15] = f2bf(gk[i][reg]);
            }
        }
    }
}

// ---------------------------------------------------------------------------
// setup conversions
__global__ __launch_bounds__(256) void w2pack_kernel(const float* __restrict__ Wq,
                                                     const float* __restrict__ Wk,
                                                     const float* __restrict__ Xi,
                                                     unsigned short* __restrict__ out)
{
    int idx = blockIdx.x * 256 + threadIdx.x;          // n*768 + d
    int d = idx % D_, n = idx / D_;
    float v;
    if (n < 768)       v = Wq[((size_t)(n >> 6) * D_ + d) * Y_ + (n & 63)];
    else if (n < 1536) { int e = n - 768; v = Wk[((size_t)(e >> 6) * D_ + d) * Y_ + (e & 63)]; }
    else               v = Xi[(size_t)d * MHID + (n - 1536)];
    out[idx] = f2bf(v);
}

__global__ __launch_bounds__(256) void bpack_kernel(const float* __restrict__ Xi,
                                                    const float* __restrict__ Wq,
                                                    const float* __restrict__ Wk,
                                                    unsigned short* __restrict__ out)
{
    int idx = blockIdx.x * 256 + threadIdx.x;          // d*4608 + c
    int c = idx % PACKLD, d = idx / PACKLD;
    float v;
    if (c < 3072)       v = Xi[(size_t)d * MHID + c];
    else if (c < 3840)  { int e = c - 3072; v = Wq[((size_t)(e >> 6) * D_ + d) * Y_ + (e & 63)]; }
    else                { int e = c - 3840; v = Wk[((size_t)(e >> 6) * D_ + d) * Y_ + (e & 63)]; }
    out[idx] = f2bf(v);
}

__global__ __launch_bounds__(256) void t768_kernel(const float* __restrict__ in,
                                                   unsigned short* __restrict__ out)
{
    int idx = blockIdx.x * 256 + threadIdx.x;          // n*768 + k
    int k = idx % D_, n = idx / D_;
    out[idx] = f2bf(in[(size_t)k * D_ + n]);
}

// ---------------------------------------------------------------------------
__global__ void mask_flags_kernel(const int* __restrict__ mask, int* __restrict__ flags)
{
    int b = threadIdx.x;
    if (b >= B_) return;
    const int* mb = mask + b * NPATCH;
    int* fb = flags + b * NPATCH;
    int cnt = 0;
    for (int n = 0; n < NPATCH; ++n) {
        int mv = mb[n];
        fb[n] = (mv == 1 && cnt < NMASK) ? 1 : 0;
        cnt += (mv == 1);
    }
    if (cnt < NMASK) fb[0] = 1;
}

__global__ __launch_bounds__(256) void patchify_kernel(const float* __restrict__ img,
                                                       unsigned short* __restrict__ patch)
{
    int idx = blockIdx.x * 256 + threadIdx.x;          // row*768 + e
    int e = idx % PELEMS, row = idx / PELEMS;
    int b = row / NPATCH, n = row % NPATCH;
    int kh = n / KW_, kw = n % KW_;
    int c = e >> 8, p = (e >> 4) & 15, q2 = e & 15;
    patch[idx] = f2bf(img[(((size_t)b * C_ + c) * H_ + kh * 16 + p) * W_ + kw * 16 + q2]);
}

__global__ __launch_bounds__(256) void build_x_kernel(const float* __restrict__ tok,
                                                      const int* __restrict__ flags,
                                                      const float* __restrict__ cls,
                                                      const float* __restrict__ mtok,
                                                      const float* __restrict__ pos,
                                                      float* __restrict__ x)
{
    int row = blockIdx.x;
    int b = row / NTOK, rr = row % NTOK;
    int tid = threadIdx.x;
#pragma unroll
    for (int i = 0; i < 3; ++i) {
        int d = tid + (i << 8);
        float v;
        if (rr == 0) v = cls[d];
        else {
            int n = rr - 1;
            v = flags[b * NPATCH + n] ? mtok[d]
                                      : tok[((size_t)b * NPATCH + n) * D_ + d];
        }
        x[(size_t)row * D_ + d] = v + pos[(size_t)rr * D_ + d];
    }
}

__global__ __launch_bounds__(256) void lnorm_kernel(const float* __restrict__ x,
                                                    unsigned short* __restrict__ g,
                                                    const float* __restrict__ gamma,
                                                    const float* __restrict__ delta)
{
    int row = blockIdx.x, tid = threadIdx.x;
    const float* xr = x + (size_t)row * D_;
    float v0 = xr[tid], v1 = xr[tid + 256], v2 = xr[tid + 512];

    __shared__ float red[256];
    red[tid] = v0 + v1 + v2;
    __syncthreads();
    for (int off = 128; off > 0; off >>= 1) {
        if (tid < off) red[tid] += red[tid + off];
        __syncthreads();
    }
    float mean = red[0] * (1.0f / D_);
    __syncthreads();
    float a0 = v0 - mean, a1 = v1 - mean, a2 = v2 - mean;
    red[tid] = a0 * a0 + a1 * a1 + a2 * a2;
    __syncthreads();
    for (int off = 128; off > 0; off >>= 1) {
        if (tid < off) red[tid] += red[tid + off];
        __syncthreads();
    }
    float var = red[0] * (1.0f / D_);
    float inv = gamma[0] / sqrtf(var + EPS_);
    unsigned short* gr = g + (size_t)row * D_;
    gr[tid]       = f2bf(a0 * inv + delta[tid]);
    gr[tid + 256] = f2bf(a1 * inv + delta[tid + 256]);
    gr[tid + 512] = f2bf(a2 * inv + delta[tid + 512]);
}

// ---------------------------------------------------------------------------
// Fused split-K reduce + x-update + layernorm (R8): x += ALPHA*(p0+p1+p2+p3),
// then lnorm(x) -> g. Replaces {atomic split-K epilogue + separate lnorm}.
__global__ __launch_bounds__(256) void upd_lnorm_kernel(
    float* __restrict__ x, const float* __restrict__ part,
    unsigned short* __restrict__ g,
    const float* __restrict__ gamma, const float* __restrict__ delta)
{
    const int row = blockIdx.x, tid = threadIdx.x;
    float* xr = x + (size_t)row * D_;
    const float* pr = part + (size_t)row * D_;
    const size_t zs = (size_t)MPAD * D_;

    float v[3];
#pragma unroll
    for (int i = 0; i < 3; ++i) {
        int d = tid + (i << 8);
        float s = pr[d] + pr[zs + d] + pr[2 * zs + d] + pr[3 * zs + d];
        v[i] = xr[d] + ALPHA_ * s;
        xr[d] = v[i];
    }

    __shared__ float red[256];
    red[tid] = v[0] + v[1] + v[2];
    __syncthreads();
    for (int off = 128; off > 0; off >>= 1) {
        if (tid < off) red[tid] += red[tid + off];
        __syncthreads();
    }
    float mean = red[0] * (1.0f / D_);
    __syncthreads();
    float a0 = v[0] - mean, a1 = v[1] - mean, a2 = v[2] - mean;
    red[tid] = a0 * a0 + a1 * a1 + a2 * a2;
    __syncthreads();
    for (int off = 128; off > 0; off >>= 1) {
        if (tid < off) red[tid] += red[tid + off];
        __syncthreads();
    }
    float var = red[0] * (1.0f / D_);
    float inv = gamma[0] / sqrtf(var + EPS_);
    unsigned short* gr = g + (size_t)row * D_;
    gr[tid]       = f2bf(a0 * inv + delta[tid]);
    gr[tid + 256] = f2bf(a1 * inv + delta[tid + 256]);
    gr[tid + 512] = f2bf(a2 * inv + delta[tid + 512]);
}

// ---------------------------------------------------------------------------
__global__ __launch_bounds__(256) void unpatch_kernel(const float* __restrict__ dec,
                                                      float* __restrict__ out)
{
    int idx = blockIdx.x * 256 + threadIdx.x;
    int ww = idx % W_;
    int t2 = idx / W_;
    int hh = t2 % H_;
    int t3 = t2 / H_;
    int c  = t3 % C_;
    int b  = t3 / C_;
    int kh = hh >> 4, p = hh & 15, kw = ww >> 4, q2 = ww & 15;
    int n = kh * KW_ + kw;
    int e = (c << 8) + (p << 4) + q2;
    out[idx] = dec[((size_t)b * NTOK + 1 + n) * D_ + e];
}

// ---------------------------------------------------------------------------
extern "C" void kernel_launch(void* const* d_in, const int* in_sizes, int n_in,
                              void* d_out, int out_size, void* d_ws, size_t ws_size,
                              hipStream_t stream)
{
    const float* img   = (const float*)d_in[0];
    const int*   mask  = (const int*)d_in[1];
    const float* enc_W = (const float*)d_in[2];
    const float* enc_b = (const float*)d_in[3];
    const float* dec_W = (const float*)d_in[4];
    const float* dec_b = (const float*)d_in[5];
    const float* cls   = (const float*)d_in[6];
    const float* mtok  = (const float*)d_in[7];
    const float* pos   = (const float*)d_in[8];
    const float* Wq    = (const float*)d_in[9];
    const float* Wk    = (const float*)d_in[10];
    const float* Xi    = (const float*)d_in[11];
    const float* gamma = (const float*)d_in[12];
    const float* delta = (const float*)d_in[13];
    float* out = (float*)d_out;

    float* ws = (float*)d_ws;
    size_t off = 0;
    auto alloc = [&](size_t nfloats) {
        off = (off + 63) & ~(size_t)63;
        float* p = ws + off; off += nfloats; return p;
    };
    float*          x    = alloc((size_t)MPAD * D_);                  // fp32
    unsigned short* g    = (unsigned short*)alloc((size_t)MPAD * D_ / 2);
    // qk bf16 [MPAD][1536]; bytes reused as dec fp32 [MPAD][768] at the end
    unsigned short* qkg  = (unsigned short*)alloc((size_t)MPAD * QKLD / 2);
    float*          decb = (float*)qkg;
    unsigned short* pack = (unsigned short*)alloc((size_t)MPAD * PACKLD / 2);
    float*          part = alloc((size_t)KSPLIT * MPAD * D_);         // fp32 partials
    unsigned short* W2   = (unsigned short*)alloc((size_t)W2LD * D_ / 2);
    unsigned short* Bpk  = (unsigned short*)alloc((size_t)D_ * PACKLD / 2);
    unsigned short* decT = (unsigned short*)alloc((size_t)D_ * D_ / 2);
    unsigned short* encT = (unsigned short*)alloc((size_t)D_ * D_ / 2);
    int*            flags = (int*)alloc(B_ * NPATCH);
    // setup-phase overlays inside pack (dead until first hid GEMM)
    unsigned short* patch = pack;                                // MPAD x 768 bf16
    float*          tok   = (float*)(pack + (size_t)MPAD * D_);  // MPAD x 768 fp32

    const dim3 blk(256);

    // ---- one-time packs ----
    w2pack_kernel<<<dim3(W2LD * D_ / 256), blk, 0, stream>>>(Wq, Wk, Xi, W2);
    bpack_kernel<<<dim3(D_ * PACKLD / 256), blk, 0, stream>>>(Xi, Wq, Wk, Bpk);
    t768_kernel<<<dim3(D_ * D_ / 256), blk, 0, stream>>>(dec_W, decT);
    t768_kernel<<<dim3(D_ * D_ / 256), blk, 0, stream>>>(enc_W, encT);
    mask_flags_kernel<<<dim3(1), dim3(64), 0, stream>>>(mask, flags);

    // ---- encode + build x ----
    patchify_kernel<<<dim3(B_ * NPATCH * PELEMS / 256), blk, 0, stream>>>(img, patch);
    mfma_gemm<0, false, true, true><<<dim3(D_ / 128, MPAD / 64), blk, 0, stream>>>(
        patch, PELEMS, encT, PELEMS, tok, D_, nullptr, enc_b, PELEMS);
    build_x_kernel<<<dim3(ROWS), blk, 0, stream>>>(tok, flags, cls, mtok, pos, x);

    // ---- energy-descent loop ----
    // g = lnorm(x) once up front; each iter: GEMM1 -> attn -> GEMM2(partials)
    // -> upd_lnorm (x += ALPHA*sum(partials); g = lnorm(x)).
    lnorm_kernel<<<dim3(ROWS), blk, 0, stream>>>(x, g, gamma, delta);
    for (int step = 0; step < NSTEPS; ++step) {
        // [qk | hid] = g @ [Wq|Wk|Xi]  (split epilogue, 64x128 tile, SWZ on)
        mfma_gemm<3, false, false, true><<<dim3(W2LD / 128, MPAD / 64), blk, 0, stream>>>(
            g, D_, W2, D_, qkg, QKLD, pack, nullptr, D_);
        // fused attention: S+softmax+Gq+Gk, all intermediates in LDS
        attn_fused_kernel<<<dim3(B_ * HEADS_), dim3(512), 0, stream>>>(qkg, pack);
        // grad partials: [hid|Gq|Gk] @ [Xi|Wq|Wk]^T  (split-K x4, SWZ off —
        // R10: swizzle regressed this latency-bound kernel 55.4 -> 63 us)
        mfma_gemm<5, false, false, false><<<dim3(D_ / 128, MPAD / 64, KSPLIT), blk, 0, stream>>>(
            pack, PACKLD, Bpk, PACKLD, part, D_, nullptr, nullptr, PACKLD / KSPLIT);
        // x += ALPHA*sum(partials); g = lnorm(x)
        upd_lnorm_kernel<<<dim3(ROWS), blk, 0, stream>>>(x, part, g, gamma, delta);
    }

    // ---- decode + unpatchify (g already = lnorm(final x)) ----
    mfma_gemm<0, false, true, true><<<dim3(D_ / 128, MPAD / 64), blk, 0, stream>>>(
        g, D_, decT, D_, decb, D_, nullptr, dec_b, D_);
    unpatch_kernel<<<dim3(B_ * C_ * H_ * W_ / 256), blk, 0, stream>>>(decb, out);
}

// Round 15
// 1809.304 us; speedup vs baseline: 1.0666x; 1.0666x over previous
//
#include <hip/hip_runtime.h>
#include <math.h>

// ---- problem constants ----
#define C_      3
#define H_      224
#define W_      224
#define KH_     14
#define KW_     14
#define NPATCH  196
#define PELEMS  768
#define D_      768
#define HEADS_  12
#define Y_      64
#define MHID    3072
#define NMASK   100
#define NSTEPS  12
#define ALPHA_  0.1f
#define BETA_   0.125f
#define EPS_    1e-5f
#define B_      16
#define NTOK    197
#define ROWS    (B_*NTOK)   /* 3152 real rows */
#define MPAD    3200        /* 50 * 64 */
#define QKLD    1536        /* fused q|k leading dim */
#define PACKLD  4608        /* hid(3072) | Gq(768) | Gk(768) */
#define W2LD    4608        /* qk(1536) | hid(3072) fused B rows */
#define KSPLIT  4           /* grad GEMM split-K (4608/4=1152=18*64).
                               R8-proven: partial-store + fused reduce, 55.4us.
                               R10/R12: XCD swizzle = noise or regression on
                               both GEMMs -> removed entirely (R13). */

typedef short short8 __attribute__((ext_vector_type(8)));
typedef unsigned short ushort8 __attribute__((ext_vector_type(8)));
typedef float floatx4 __attribute__((ext_vector_type(4)));

__device__ __forceinline__ unsigned short f2bf(float f) {
    union { float f; unsigned u; } v; v.f = f;
    unsigned r = (v.u + 0x7FFFu + ((v.u >> 16) & 1u)) >> 16;
    return (unsigned short)r;
}
__device__ __forceinline__ float bf2f(unsigned short u) {
    union { unsigned u; float f; } v; v.u = ((unsigned)u) << 16;
    return v.f;
}

__device__ __forceinline__ void async_cp16(const void* g, void* l) {
    __builtin_amdgcn_global_load_lds(
        (const __attribute__((address_space(1))) unsigned int*)g,
        (__attribute__((address_space(3))) unsigned int*)l, 16, 0, 0);
}

// ---------------------------------------------------------------------------
// MFMA bf16 NT GEMM: C[M][N] = A(MxK bf16) @ B(NxK bf16)^T.
// 64x128 tile, BK=64/iter, single-buffer 2-barrier loop (R2/R8-proven best:
// explicit dbuf WORSE (R7, occupancy 35->25%); XCD swizzle noise/regression
// (R10/R12) — removed).
// OUT_MODE: 0 = fp32 store, 1 = bf16 store,
//           3 = split epilogue: col<1536 -> Cout bf16 (ld QKLD), else relu ->
//               Cout2 bf16 (ld PACKLD, col-1536)
//           5 = split-K partial: koff = blockIdx.z*K, plain fp32 store to
//               Cout + z*MPAD*D_ (no atomics; reduced in upd_lnorm_kernel)
template<int OUT_MODE, bool RELU, bool HAS_BIAS>
__global__ __launch_bounds__(256) void mfma_gemm(
    const unsigned short* __restrict__ A, int lda,
    const unsigned short* __restrict__ B, int ldb,
    void* __restrict__ Cout, int ldc, void* __restrict__ Cout2,
    const float* __restrict__ bias, int K)
{
    __shared__ alignas(16) unsigned short ldsA[2][64 * 32];
    __shared__ alignas(16) unsigned short ldsB[2][128 * 32];

    const int bx = blockIdx.x, by = blockIdx.y;
    const int koff = (OUT_MODE == 5) ? blockIdx.z * K : 0;

    const int t    = threadIdx.x;
    const int wave = t >> 6;
    const int lane = t & 63;
    const int row0 = by << 6;
    const int col0 = bx << 7;
    const int wm = (wave & 1) << 5;
    const int wn = (wave >> 1) << 6;
    const int r  = lane & 15;
    const int qd = lane >> 4;

    const unsigned short* Abase = A + (size_t)row0 * lda + koff;
    const unsigned short* Bbase = B + (size_t)col0 * ldb + koff;

    floatx4 acc[2][4];
#pragma unroll
    for (int i = 0; i < 2; ++i)
#pragma unroll
        for (int j = 0; j < 4; ++j)
            acc[i][j] = (floatx4){0.f, 0.f, 0.f, 0.f};

    const int crow = t >> 2;
    const int coff = (t & 3) << 3;
    for (int k0 = 0; k0 < K; k0 += 64) {
#pragma unroll
        for (int kb = 0; kb < 2; ++kb) {
            const int kk = k0 + kb * 32;
            async_cp16(Abase + (size_t)crow * lda + kk + coff,
                       ldsA[kb] + (wave << 9));
            async_cp16(Bbase + (size_t)crow * ldb + kk + coff,
                       ldsB[kb] + (wave << 9));
            async_cp16(Bbase + (size_t)(64 + crow) * ldb + kk + coff,
                       ldsB[kb] + 2048 + (wave << 9));
        }
        __syncthreads();
#pragma unroll
        for (int kb = 0; kb < 2; ++kb) {
            short8 af[2], bfr[4];
#pragma unroll
            for (int i = 0; i < 2; ++i)
                af[i]  = *(const short8*)&ldsA[kb][(wm + (i << 4) + r) * 32 + (qd << 3)];
#pragma unroll
            for (int j = 0; j < 4; ++j)
                bfr[j] = *(const short8*)&ldsB[kb][(wn + (j << 4) + r) * 32 + (qd << 3)];
#pragma unroll
            for (int i = 0; i < 2; ++i)
#pragma unroll
                for (int j = 0; j < 4; ++j)
                    acc[i][j] = __builtin_amdgcn_mfma_f32_16x16x32_bf16(
                                    af[i], bfr[j], acc[i][j], 0, 0, 0);
        }
        __syncthreads();
    }

    float* Cpart = (OUT_MODE == 5)
        ? (float*)Cout + (size_t)blockIdx.z * ((size_t)MPAD * D_) : (float*)Cout;

#pragma unroll
    for (int i = 0; i < 2; ++i) {
#pragma unroll
        for (int j = 0; j < 4; ++j) {
            int cc = col0 + wn + (j << 4) + r;
#pragma unroll
            for (int reg = 0; reg < 4; ++reg) {
                int rr = row0 + wm + (i << 4) + (qd << 2) + reg;
                float v = acc[i][j][reg];
                if (HAS_BIAS) v += bias[cc];
                if (RELU)     v = fmaxf(v, 0.f);
                if (OUT_MODE == 1)
                    ((unsigned short*)Cout)[(size_t)rr * ldc + cc] = f2bf(v);
                else if (OUT_MODE == 3) {
                    if (cc < QKLD)
                        ((unsigned short*)Cout)[(size_t)rr * QKLD + cc] = f2bf(v);
                    else
                        ((unsigned short*)Cout2)[(size_t)rr * PACKLD + (cc - QKLD)]
                            = f2bf(fmaxf(v, 0.f));
                } else if (OUT_MODE == 5)
                    Cpart[(size_t)rr * ldc + cc] = v;
                else
                    ((float*)Cout)[(size_t)rr * ldc + cc] = v;
            }
        }
    }
}

// ---------------------------------------------------------------------------
// Fused attention: replaces tqk + attn_pgq + attn_pv.
// One block per (b,h): grid 192, 512 threads (8 waves), 128,000 B LDS.
//   Ks  [208][72]  bf16  K_h m-major (m>=197 zero)          29,952 B
//   Kt  [64][232]  bf16  K_h y-major (m-cols 197..223 zero) 29,696 B
//   Qc  [32][72]   bf16  Q n-chunk (rows>=csz zero)          4,608 B
//   Qtc [64][40]   bf16  Q-chunk y-major (n-cols>=csz zero)  5,120 B
//   Pb  [32][232]  bf16  P chunk n-major (cols>=197 zero)   14,848 B
//   PTb [208][40]  bf16  P chunk m-major                    16,640 B
//   Pm  [32][212]  fp32  S / softmax scratch                27,136 B
// Per chunk: S = Qc @ Ks^T (MFMA) -> softmax (beta in exp, m>=NTOK masked)
// -> Pb/PTb -> Gq = Pb @ Kt^T stored to pack[3072..], Gk += PTb @ Qtc^T
// accumulated in registers (7 statically-indexed floatx4), stored at end to
// pack[3840..]. P/PT/kT/qT never touch global memory.
__global__ __launch_bounds__(512) void attn_fused_kernel(
    const unsigned short* __restrict__ qk,   // bf16 [MPAD][1536]
    unsigned short* __restrict__ pack)       // bf16 [MPAD][4608]
{
    __shared__ alignas(16) unsigned short Ks[208 * 72];
    __shared__ alignas(16) unsigned short Kt[64 * 232];
    __shared__ alignas(16) unsigned short Qc[32 * 72];
    __shared__ alignas(16) unsigned short Qtc[64 * 40];
    __shared__ alignas(16) unsigned short Pb[32 * 232];
    __shared__ alignas(16) unsigned short PTb[208 * 40];
    __shared__ alignas(16) float Pm[32 * 212];

    const int bh = blockIdx.x;
    const int h = bh % HEADS_, b = bh / HEADS_;
    const int t = threadIdx.x;
    const int lane = t & 63, wave = t >> 6;
    const int ln15 = lane & 15, quad = lane >> 4;
    const size_t rowbase = (size_t)(b * NTOK) * QKLD;
    const int hoff = h * 64;

    // ---- phase 0: load K_h (zero-padded to 208 rows), zero Pb/PTb ----
    for (int idx = t; idx < 208 * 8; idx += 512) {
        int m = idx >> 3, c8 = idx & 7;
        uint4 v = (uint4){0, 0, 0, 0};
        if (m < NTOK)
            v = *(const uint4*)&qk[rowbase + (size_t)m * QKLD + 768 + hoff + c8 * 8];
        *(uint4*)&Ks[m * 72 + c8 * 8] = v;
    }
    for (int idx = t; idx < (32 * 232) / 8; idx += 512)
        *(uint4*)&Pb[idx * 8] = (uint4){0, 0, 0, 0};
    for (int idx = t; idx < (208 * 40) / 8; idx += 512)
        *(uint4*)&PTb[idx * 8] = (uint4){0, 0, 0, 0};
    __syncthreads();

    // ---- build Kt[y][m] = Ks[m][y]  (m 0..223, zeros past 207) ----
    for (int idx = t; idx < 64 * 112; idx += 512) {
        int y = idx / 112, mp = idx % 112;
        int m0 = 2 * mp;
        unsigned lo = (m0     < 208) ? Ks[(m0    ) * 72 + y] : 0u;
        unsigned hi = (m0 + 1 < 208) ? Ks[(m0 + 1) * 72 + y] : 0u;
        *(unsigned*)&Kt[y * 232 + m0] = lo | (hi << 16);
    }
    __syncthreads();

    // ---- Gk accumulators: 52 (mt,yt) tiles over 8 waves, static index ----
    floatx4 gk[7];
#pragma unroll
    for (int i = 0; i < 7; ++i) gk[i] = (floatx4){0.f, 0.f, 0.f, 0.f};

    for (int nc = 0; nc < 7; ++nc) {
        const int n0 = nc * 32;
        const int csz = (NTOK - n0 < 32) ? (NTOK - n0) : 32;

        // -- load Q chunk (rows >= csz zeroed) --
        for (int idx = t; idx < 32 * 8; idx += 512) {
            int nn = idx >> 3, c8 = idx & 7;
            uint4 v = (uint4){0, 0, 0, 0};
            if (nn < csz)
                v = *(const uint4*)&qk[rowbase + (size_t)(n0 + nn) * QKLD + hoff + c8 * 8];
            *(uint4*)&Qc[nn * 72 + c8 * 8] = v;
        }
        __syncthreads();   // bar1: Qc ready; prev-iter Gq/Gk done (Qtc safe)

        // -- build Qtc[y][nn] = Qc[nn][y]  (cols >= csz zero via Qc pad) --
        for (int idx = t; idx < 64 * 16; idx += 512) {
            int y = idx >> 4, np = idx & 15;
            unsigned lo = Qc[(2 * np    ) * 72 + y];
            unsigned hi = Qc[(2 * np + 1) * 72 + y];
            *(unsigned*)&Qtc[y * 40 + 2 * np] = lo | (hi << 16);
        }

        // -- S = Qc @ Ks^T  (waves split the 13 m-tiles) --
        {
            short8 aq[2][2];
#pragma unroll
            for (int nt = 0; nt < 2; ++nt)
#pragma unroll
                for (int kb = 0; kb < 2; ++kb)
                    aq[nt][kb] = *(const short8*)
                        &Qc[(nt * 16 + ln15) * 72 + kb * 32 + quad * 8];

            for (int mt = wave; mt < 13; mt += 8) {
                short8 b0 = *(const short8*)&Ks[(mt * 16 + ln15) * 72 + quad * 8];
                short8 b1 = *(const short8*)&Ks[(mt * 16 + ln15) * 72 + 32 + quad * 8];
                floatx4 s0 = (floatx4){0.f, 0.f, 0.f, 0.f};
                floatx4 s1 = (floatx4){0.f, 0.f, 0.f, 0.f};
                s0 = __builtin_amdgcn_mfma_f32_16x16x32_bf16(aq[0][0], b0, s0, 0, 0, 0);
                s0 = __builtin_amdgcn_mfma_f32_16x16x32_bf16(aq[0][1], b1, s0, 0, 0, 0);
                s1 = __builtin_amdgcn_mfma_f32_16x16x32_bf16(aq[1][0], b0, s1, 0, 0, 0);
                s1 = __builtin_amdgcn_mfma_f32_16x16x32_bf16(aq[1][1], b1, s1, 0, 0, 0);
#pragma unroll
                for (int reg = 0; reg < 4; ++reg) {
                    Pm[(quad * 4 + reg) * 212 + mt * 16 + ln15]      = s0[reg];
                    Pm[(16 + quad * 4 + reg) * 212 + mt * 16 + ln15] = s1[reg];
                }
            }
        }
        __syncthreads();   // bar2: Pm ready

        // -- softmax rows (beta inside exp); emit Pb (n-major) + PTb (m-major)
        for (int nn = wave; nn < csz; nn += 8) {
            float v0 = Pm[nn * 212 + lane];
            float v1 = (lane +  64 < NTOK) ? Pm[nn * 212 + lane +  64] : -1e30f;
            float v2 = (lane + 128 < NTOK) ? Pm[nn * 212 + lane + 128] : -1e30f;
            float v3 = (lane + 192 < NTOK) ? Pm[nn * 212 + lane + 192] : -1e30f;
            float mx = fmaxf(fmaxf(v0, v1), fmaxf(v2, v3));
#pragma unroll
            for (int o = 32; o > 0; o >>= 1) mx = fmaxf(mx, __shfl_xor(mx, o, 64));
            float e0 = __expf((v0 - mx) * BETA_);
            float e1 = (lane +  64 < NTOK) ? __expf((v1 - mx) * BETA_) : 0.f;
            float e2 = (lane + 128 < NTOK) ? __expf((v2 - mx) * BETA_) : 0.f;
            float e3 = (lane + 192 < NTOK) ? __expf((v3 - mx) * BETA_) : 0.f;
            float s = e0 + e1 + e2 + e3;
#pragma unroll
            for (int o = 32; o > 0; o >>= 1) s += __shfl_xor(s, o, 64);
            float inv = 1.0f / s;
            {
                unsigned short p = f2bf(e0 * inv);
                Pb[nn * 232 + lane] = p;
                PTb[lane * 40 + nn] = p;
            }
            {
                unsigned short p = f2bf(e1 * inv);
                Pb[nn * 232 + lane + 64] = p;
                PTb[(lane + 64) * 40 + nn] = p;
            }
            {
                unsigned short p = f2bf(e2 * inv);
                Pb[nn * 232 + lane + 128] = p;
                PTb[(lane + 128) * 40 + nn] = p;
            }
            if (lane + 192 < NTOK) {
                unsigned short p = f2bf(e3 * inv);
                Pb[nn * 232 + lane + 192] = p;
                PTb[(lane + 192) * 40 + nn] = p;
            }
        }
        __syncthreads();   // bar3: Pb/PTb ready

        // -- Gq = Pb @ Kt^T : 8 output tiles, one per wave; store to pack --
        {
            const int nt = wave >> 2, yt = wave & 3;
            floatx4 gq = (floatx4){0.f, 0.f, 0.f, 0.f};
#pragma unroll
            for (int ks = 0; ks < 7; ++ks) {
                short8 a  = *(const short8*)&Pb[(nt * 16 + ln15) * 232 + ks * 32 + quad * 8];
                short8 bk = *(const short8*)&Kt[(yt * 16 + ln15) * 232 + ks * 32 + quad * 8];
                gq = __builtin_amdgcn_mfma_f32_16x16x32_bf16(a, bk, gq, 0, 0, 0);
            }
#pragma unroll
            for (int reg = 0; reg < 4; ++reg) {
                int row = nt * 16 + quad * 4 + reg;
                if (row < csz)
                    pack[(size_t)(b * NTOK + n0 + row) * PACKLD
                         + 3072 + hoff + yt * 16 + ln15] = f2bf(gq[reg]);
            }
        }

        // -- Gk += PTb @ Qtc^T : 52 tiles over 8 waves (static acc index) --
#pragma unroll
        for (int i = 0; i < 7; ++i) {
            int ti = wave + i * 8;
            if (ti < 52) {
                int mt = ti >> 2, yt = ti & 3;
                short8 a  = *(const short8*)&PTb[(mt * 16 + ln15) * 40 + quad * 8];
                short8 bq = *(const short8*)&Qtc[(yt * 16 + ln15) * 40 + quad * 8];
                gk[i] = __builtin_amdgcn_mfma_f32_16x16x32_bf16(a, bq, gk[i], 0, 0, 0);
            }
        }
    }

    // ---- store Gk ----
#pragma unroll
    for (int i = 0; i < 7; ++i) {
        int ti = wave + i * 8;
        if (ti < 52) {
            int mt = ti >> 2, yt = ti & 3;
#pragma unroll
            for (int reg = 0; reg < 4; ++reg) {
                int m = mt * 16 + quad * 4 + reg;
                if (m < NTOK)
                    pack[(size_t)(b * NTOK + m) * PACKLD
                         + 3840 + hoff + yt * 16 + ln15] = f2bf(gk[i][reg]);
            }
        }
    }
}

// ---------------------------------------------------------------------------
// setup conversions
__global__ __launch_bounds__(256) void w2pack_kernel(const float* __restrict__ Wq,
                                                     const float* __restrict__ Wk,
                                                     const float* __restrict__ Xi,
                                                     unsigned short* __restrict__ out)
{
    int idx = blockIdx.x * 256 + threadIdx.x;          // n*768 + d
    int d = idx % D_, n = idx / D_;
    float v;
    if (n < 768)       v = Wq[((size_t)(n >> 6) * D_ + d) * Y_ + (n & 63)];
    else if (n < 1536) { int e = n - 768; v = Wk[((size_t)(e >> 6) * D_ + d) * Y_ + (e & 63)]; }
    else               v = Xi[(size_t)d * MHID + (n - 1536)];
    out[idx] = f2bf(v);
}

__global__ __launch_bounds__(256) void bpack_kernel(const float* __restrict__ Xi,
                                                    const float* __restrict__ Wq,
                                                    const float* __restrict__ Wk,
                                                    unsigned short* __restrict__ out)
{
    int idx = blockIdx.x * 256 + threadIdx.x;          // d*4608 + c
    int c = idx % PACKLD, d = idx / PACKLD;
    float v;
    if (c < 3072)       v = Xi[(size_t)d * MHID + c];
    else if (c < 3840)  { int e = c - 3072; v = Wq[((size_t)(e >> 6) * D_ + d) * Y_ + (e & 63)]; }
    else                { int e = c - 3840; v = Wk[((size_t)(e >> 6) * D_ + d) * Y_ + (e & 63)]; }
    out[idx] = f2bf(v);
}

__global__ __launch_bounds__(256) void t768_kernel(const float* __restrict__ in,
                                                   unsigned short* __restrict__ out)
{
    int idx = blockIdx.x * 256 + threadIdx.x;          // n*768 + k
    int k = idx % D_, n = idx / D_;
    out[idx] = f2bf(in[(size_t)k * D_ + n]);
}

// ---------------------------------------------------------------------------
__global__ void mask_flags_kernel(const int* __restrict__ mask, int* __restrict__ flags)
{
    int b = threadIdx.x;
    if (b >= B_) return;
    const int* mb = mask + b * NPATCH;
    int* fb = flags + b * NPATCH;
    int cnt = 0;
    for (int n = 0; n < NPATCH; ++n) {
        int mv = mb[n];
        fb[n] = (mv == 1 && cnt < NMASK) ? 1 : 0;
        cnt += (mv == 1);
    }
    if (cnt < NMASK) fb[0] = 1;
}

__global__ __launch_bounds__(256) void patchify_kernel(const float* __restrict__ img,
                                                       unsigned short* __restrict__ patch)
{
    int idx = blockIdx.x * 256 + threadIdx.x;          // row*768 + e
    int e = idx % PELEMS, row = idx / PELEMS;
    int b = row / NPATCH, n = row % NPATCH;
    int kh = n / KW_, kw = n % KW_;
    int c = e >> 8, p = (e >> 4) & 15, q2 = e & 15;
    patch[idx] = f2bf(img[(((size_t)b * C_ + c) * H_ + kh * 16 + p) * W_ + kw * 16 + q2]);
}

__global__ __launch_bounds__(256) void build_x_kernel(const float* __restrict__ tok,
                                                      const int* __restrict__ flags,
                                                      const float* __restrict__ cls,
                                                      const float* __restrict__ mtok,
                                                      const float* __restrict__ pos,
                                                      float* __restrict__ x)
{
    int row = blockIdx.x;
    int b = row / NTOK, rr = row % NTOK;
    int tid = threadIdx.x;
#pragma unroll
    for (int i = 0; i < 3; ++i) {
        int d = tid + (i << 8);
        float v;
        if (rr == 0) v = cls[d];
        else {
            int n = rr - 1;
            v = flags[b * NPATCH + n] ? mtok[d]
                                      : tok[((size_t)b * NPATCH + n) * D_ + d];
        }
        x[(size_t)row * D_ + d] = v + pos[(size_t)rr * D_ + d];
    }
}

// ---------------------------------------------------------------------------
// Vectorized layernorm (R13): 192 active lanes x float4 (16B/lane) — G13,
// hipcc does not auto-vectorize the scalar fp32 loads. Same arithmetic.
__global__ __launch_bounds__(256) void lnorm_kernel(const float* __restrict__ x,
                                                    unsigned short* __restrict__ g,
                                                    const float* __restrict__ gamma,
                                                    const float* __restrict__ delta)
{
    int row = blockIdx.x, tid = threadIdx.x;
    const float* xr = x + (size_t)row * D_;
    const bool act = tid < 192;
    float4 v = act ? *(const float4*)&xr[tid * 4]
                   : make_float4(0.f, 0.f, 0.f, 0.f);

    __shared__ float red[256];
    red[tid] = v.x + v.y + v.z + v.w;
    __syncthreads();
    for (int off = 128; off > 0; off >>= 1) {
        if (tid < off) red[tid] += red[tid + off];
        __syncthreads();
    }
    float mean = red[0] * (1.0f / D_);
    __syncthreads();
    float a0 = v.x - mean, a1 = v.y - mean, a2 = v.z - mean, a3 = v.w - mean;
    red[tid] = act ? (a0 * a0 + a1 * a1 + a2 * a2 + a3 * a3) : 0.f;
    __syncthreads();
    for (int off = 128; off > 0; off >>= 1) {
        if (tid < off) red[tid] += red[tid + off];
        __syncthreads();
    }
    float var = red[0] * (1.0f / D_);
    float inv = gamma[0] / sqrtf(var + EPS_);
    if (act) {
        float4 dl = *(const float4*)&delta[tid * 4];
        ushort4 o;
        o.x = f2bf(a0 * inv + dl.x);
        o.y = f2bf(a1 * inv + dl.y);
        o.z = f2bf(a2 * inv + dl.z);
        o.w = f2bf(a3 * inv + dl.w);
        *(ushort4*)&g[(size_t)row * D_ + tid * 4] = o;
    }
}

// ---------------------------------------------------------------------------
// Fused split-K reduce + x-update + layernorm (R8, vectorized R13):
// x += ALPHA*(p0+p1+p2+p3), then lnorm(x) -> g. 192 lanes x float4; the
// 5 input streams + x-write are 16B/lane coalesced.
__global__ __launch_bounds__(256) void upd_lnorm_kernel(
    float* __restrict__ x, const float* __restrict__ part,
    unsigned short* __restrict__ g,
    const float* __restrict__ gamma, const float* __restrict__ delta)
{
    const int row = blockIdx.x, tid = threadIdx.x;
    float* xr = x + (size_t)row * D_;
    const float* pr = part + (size_t)row * D_;
    const size_t zs = (size_t)MPAD * D_;
    const bool act = tid < 192;

    float4 v = make_float4(0.f, 0.f, 0.f, 0.f);
    if (act) {
        const int d = tid * 4;
        float4 p0 = *(const float4*)&pr[d];
        float4 p1 = *(const float4*)&pr[zs + d];
        float4 p2 = *(const float4*)&pr[2 * zs + d];
        float4 p3 = *(const float4*)&pr[3 * zs + d];
        float4 xv = *(const float4*)&xr[d];
        v.x = xv.x + ALPHA_ * (p0.x + p1.x + p2.x + p3.x);
        v.y = xv.y + ALPHA_ * (p0.y + p1.y + p2.y + p3.y);
        v.z = xv.z + ALPHA_ * (p0.z + p1.z + p2.z + p3.z);
        v.w = xv.w + ALPHA_ * (p0.w + p1.w + p2.w + p3.w);
        *(float4*)&xr[d] = v;
    }

    __shared__ float red[256];
    red[tid] = v.x + v.y + v.z + v.w;
    __syncthreads();
    for (int off = 128; off > 0; off >>= 1) {
        if (tid < off) red[tid] += red[tid + off];
        __syncthreads();
    }
    float mean = red[0] * (1.0f / D_);
    __syncthreads();
    float a0 = v.x - mean, a1 = v.y - mean, a2 = v.z - mean, a3 = v.w - mean;
    red[tid] = act ? (a0 * a0 + a1 * a1 + a2 * a2 + a3 * a3) : 0.f;
    __syncthreads();
    for (int off = 128; off > 0; off >>= 1) {
        if (tid < off) red[tid] += red[tid + off];
        __syncthreads();
    }
    float var = red[0] * (1.0f / D_);
    float inv = gamma[0] / sqrtf(var + EPS_);
    if (act) {
        float4 dl = *(const float4*)&delta[tid * 4];
        ushort4 o;
        o.x = f2bf(a0 * inv + dl.x);
        o.y = f2bf(a1 * inv + dl.y);
        o.z = f2bf(a2 * inv + dl.z);
        o.w = f2bf(a3 * inv + dl.w);
        *(ushort4*)&g[(size_t)row * D_ + tid * 4] = o;
    }
}

// ---------------------------------------------------------------------------
__global__ __launch_bounds__(256) void unpatch_kernel(const float* __restrict__ dec,
                                                      float* __restrict__ out)
{
    int idx = blockIdx.x * 256 + threadIdx.x;
    int ww = idx % W_;
    int t2 = idx / W_;
    int hh = t2 % H_;
    int t3 = t2 / H_;
    int c  = t3 % C_;
    int b  = t3 / C_;
    int kh = hh >> 4, p = hh & 15, kw = ww >> 4, q2 = ww & 15;
    int n = kh * KW_ + kw;
    int e = (c << 8) + (p << 4) + q2;
    out[idx] = dec[((size_t)b * NTOK + 1 + n) * D_ + e];
}

// ---------------------------------------------------------------------------
extern "C" void kernel_launch(void* const* d_in, const int* in_sizes, int n_in,
                              void* d_out, int out_size, void* d_ws, size_t ws_size,
                              hipStream_t stream)
{
    const float* img   = (const float*)d_in[0];
    const int*   mask  = (const int*)d_in[1];
    const float* enc_W = (const float*)d_in[2];
    const float* enc_b = (const float*)d_in[3];
    const float* dec_W = (const float*)d_in[4];
    const float* dec_b = (const float*)d_in[5];
    const float* cls   = (const float*)d_in[6];
    const float* mtok  = (const float*)d_in[7];
    const float* pos   = (const float*)d_in[8];
    const float* Wq    = (const float*)d_in[9];
    const float* Wk    = (const float*)d_in[10];
    const float* Xi    = (const float*)d_in[11];
    const float* gamma = (const float*)d_in[12];
    const float* delta = (const float*)d_in[13];
    float* out = (float*)d_out;

    float* ws = (float*)d_ws;
    size_t off = 0;
    auto alloc = [&](size_t nfloats) {
        off = (off + 63) & ~(size_t)63;
        float* p = ws + off; off += nfloats; return p;
    };
    float*          x    = alloc((size_t)MPAD * D_);                  // fp32
    unsigned short* g    = (unsigned short*)alloc((size_t)MPAD * D_ / 2);
    // qk bf16 [MPAD][1536]; bytes reused as dec fp32 [MPAD][768] at the end
    unsigned short* qkg  = (unsigned short*)alloc((size_t)MPAD * QKLD / 2);
    float*          decb = (float*)qkg;
    unsigned short* pack = (unsigned short*)alloc((size_t)MPAD * PACKLD / 2);
    float*          part = alloc((size_t)KSPLIT * MPAD * D_);         // fp32 partials
    unsigned short* W2   = (unsigned short*)alloc((size_t)W2LD * D_ / 2);
    unsigned short* Bpk  = (unsigned short*)alloc((size_t)D_ * PACKLD / 2);
    unsigned short* decT = (unsigned short*)alloc((size_t)D_ * D_ / 2);
    unsigned short* encT = (unsigned short*)alloc((size_t)D_ * D_ / 2);
    int*            flags = (int*)alloc(B_ * NPATCH);
    // setup-phase overlays inside pack (dead until first hid GEMM)
    unsigned short* patch = pack;                                // MPAD x 768 bf16
    float*          tok   = (float*)(pack + (size_t)MPAD * D_);  // MPAD x 768 fp32

    const dim3 blk(256);

    // ---- one-time packs ----
    w2pack_kernel<<<dim3(W2LD * D_ / 256), blk, 0, stream>>>(Wq, Wk, Xi, W2);
    bpack_kernel<<<dim3(D_ * PACKLD / 256), blk, 0, stream>>>(Xi, Wq, Wk, Bpk);
    t768_kernel<<<dim3(D_ * D_ / 256), blk, 0, stream>>>(dec_W, decT);
    t768_kernel<<<dim3(D_ * D_ / 256), blk, 0, stream>>>(enc_W, encT);
    mask_flags_kernel<<<dim3(1), dim3(64), 0, stream>>>(mask, flags);

    // ---- encode + build x ----
    patchify_kernel<<<dim3(B_ * NPATCH * PELEMS / 256), blk, 0, stream>>>(img, patch);
    mfma_gemm<0, false, true><<<dim3(D_ / 128, MPAD / 64), blk, 0, stream>>>(
        patch, PELEMS, encT, PELEMS, tok, D_, nullptr, enc_b, PELEMS);
    build_x_kernel<<<dim3(ROWS), blk, 0, stream>>>(tok, flags, cls, mtok, pos, x);

    // ---- energy-descent loop ----
    // g = lnorm(x) once up front; each iter: GEMM1 -> attn -> GEMM2(partials)
    // -> upd_lnorm (x += ALPHA*sum(partials); g = lnorm(x)).
    lnorm_kernel<<<dim3(ROWS), blk, 0, stream>>>(x, g, gamma, delta);
    for (int step = 0; step < NSTEPS; ++step) {
        // [qk | hid] = g @ [Wq|Wk|Xi]  (split epilogue, 64x128 tile)
        mfma_gemm<3, false, false><<<dim3(W2LD / 128, MPAD / 64), blk, 0, stream>>>(
            g, D_, W2, D_, qkg, QKLD, pack, nullptr, D_);
        // fused attention: S+softmax+Gq+Gk, all intermediates in LDS
        attn_fused_kernel<<<dim3(B_ * HEADS_), dim3(512), 0, stream>>>(qkg, pack);
        // grad partials: [hid|Gq|Gk] @ [Xi|Wq|Wk]^T  (split-K x4, plain stores)
        mfma_gemm<5, false, false><<<dim3(D_ / 128, MPAD / 64, KSPLIT), blk, 0, stream>>>(
            pack, PACKLD, Bpk, PACKLD, part, D_, nullptr, nullptr, PACKLD / KSPLIT);
        // x += ALPHA*sum(partials); g = lnorm(x)
        upd_lnorm_kernel<<<dim3(ROWS), blk, 0, stream>>>(x, part, g, gamma, delta);
    }

    // ---- decode + unpatchify (g already = lnorm(final x)) ----
    mfma_gemm<0, false, true><<<dim3(D_ / 128, MPAD / 64), blk, 0, stream>>>(
        g, D_, decT, D_, decb, D_, nullptr, dec_b, D_);
    unpatch_kernel<<<dim3(B_ * C_ * H_ * W_ / 256), blk, 0, stream>>>(decb, out);
}

// Round 16
// 1792.320 us; speedup vs baseline: 1.0768x; 1.0095x over previous
//
#include <hip/hip_runtime.h>
#include <math.h>

// ---- problem constants ----
#define C_      3
#define H_      224
#define W_      224
#define KH_     14
#define KW_     14
#define NPATCH  196
#define PELEMS  768
#define D_      768
#define HEADS_  12
#define Y_      64
#define MHID    3072
#define NMASK   100
#define NSTEPS  12
#define ALPHA_  0.1f
#define BETA_   0.125f
#define EPS_    1e-5f
#define B_      16
#define NTOK    197
#define ROWS    (B_*NTOK)   /* 3152 real rows */
#define MPAD    3200        /* 50 * 64 */
#define QKLD    1536        /* fused q|k leading dim */
#define PACKLD  4608        /* hid(3072) | Gq(768) | Gk(768) */
#define W2LD    4608        /* qk(1536) | hid(3072) fused B rows */
#define KSPLIT  4           /* grad GEMM split-K (4608/4=1152=18*64).
                               R8-proven: partial-store + fused reduce, 55.4us.
                               R5/R7/R10/R12: KSPLIT=2, dbuf, XCD swizzle all
                               measured worse/noise -> structure frozen. */

typedef short short8 __attribute__((ext_vector_type(8)));
typedef unsigned short ushort8 __attribute__((ext_vector_type(8)));
typedef float floatx4 __attribute__((ext_vector_type(4)));

__device__ __forceinline__ unsigned short f2bf(float f) {
    union { float f; unsigned u; } v; v.f = f;
    unsigned r = (v.u + 0x7FFFu + ((v.u >> 16) & 1u)) >> 16;
    return (unsigned short)r;
}
__device__ __forceinline__ float bf2f(unsigned short u) {
    union { unsigned u; float f; } v; v.u = ((unsigned)u) << 16;
    return v.f;
}

__device__ __forceinline__ void async_cp16(const void* g, void* l) {
    __builtin_amdgcn_global_load_lds(
        (const __attribute__((address_space(1))) unsigned int*)g,
        (__attribute__((address_space(3))) unsigned int*)l, 16, 0, 0);
}

// ---------------------------------------------------------------------------
// MFMA bf16 NT GEMM: C[M][N] = A(MxK bf16) @ B(NxK bf16)^T.
// 64x128 tile, BK=64/iter, single-buffer 2-barrier loop (R2/R8-proven best).
// OUT_MODE: 0 = fp32 store, 1 = bf16 store,
//           3 = split epilogue: col<1536 -> Cout bf16 (ld QKLD), else relu ->
//               Cout2 bf16 (ld PACKLD, col-1536)
//           5 = split-K partial: koff = blockIdx.z*K, plain fp32 store to
//               Cout + z*MPAD*D_ (no atomics; reduced in upd_lnorm_kernel)
//           6 = decode: fp32 direct to out[B][C][H][W] (fused unpatchify,
//               R16 — removes the decb round-trip + unpatch launch)
template<int OUT_MODE, bool RELU, bool HAS_BIAS>
__global__ __launch_bounds__(256) void mfma_gemm(
    const unsigned short* __restrict__ A, int lda,
    const unsigned short* __restrict__ B, int ldb,
    void* __restrict__ Cout, int ldc, void* __restrict__ Cout2,
    const float* __restrict__ bias, int K)
{
    __shared__ alignas(16) unsigned short ldsA[2][64 * 32];
    __shared__ alignas(16) unsigned short ldsB[2][128 * 32];

    const int bx = blockIdx.x, by = blockIdx.y;
    const int koff = (OUT_MODE == 5) ? blockIdx.z * K : 0;

    const int t    = threadIdx.x;
    const int wave = t >> 6;
    const int lane = t & 63;
    const int row0 = by << 6;
    const int col0 = bx << 7;
    const int wm = (wave & 1) << 5;
    const int wn = (wave >> 1) << 6;
    const int r  = lane & 15;
    const int qd = lane >> 4;

    const unsigned short* Abase = A + (size_t)row0 * lda + koff;
    const unsigned short* Bbase = B + (size_t)col0 * ldb + koff;

    floatx4 acc[2][4];
#pragma unroll
    for (int i = 0; i < 2; ++i)
#pragma unroll
        for (int j = 0; j < 4; ++j)
            acc[i][j] = (floatx4){0.f, 0.f, 0.f, 0.f};

    const int crow = t >> 2;
    const int coff = (t & 3) << 3;
    for (int k0 = 0; k0 < K; k0 += 64) {
#pragma unroll
        for (int kb = 0; kb < 2; ++kb) {
            const int kk = k0 + kb * 32;
            async_cp16(Abase + (size_t)crow * lda + kk + coff,
                       ldsA[kb] + (wave << 9));
            async_cp16(Bbase + (size_t)crow * ldb + kk + coff,
                       ldsB[kb] + (wave << 9));
            async_cp16(Bbase + (size_t)(64 + crow) * ldb + kk + coff,
                       ldsB[kb] + 2048 + (wave << 9));
        }
        __syncthreads();
#pragma unroll
        for (int kb = 0; kb < 2; ++kb) {
            short8 af[2], bfr[4];
#pragma unroll
            for (int i = 0; i < 2; ++i)
                af[i]  = *(const short8*)&ldsA[kb][(wm + (i << 4) + r) * 32 + (qd << 3)];
#pragma unroll
            for (int j = 0; j < 4; ++j)
                bfr[j] = *(const short8*)&ldsB[kb][(wn + (j << 4) + r) * 32 + (qd << 3)];
#pragma unroll
            for (int i = 0; i < 2; ++i)
#pragma unroll
                for (int j = 0; j < 4; ++j)
                    acc[i][j] = __builtin_amdgcn_mfma_f32_16x16x32_bf16(
                                    af[i], bfr[j], acc[i][j], 0, 0, 0);
        }
        __syncthreads();
    }

    float* Cpart = (OUT_MODE == 5)
        ? (float*)Cout + (size_t)blockIdx.z * ((size_t)MPAD * D_) : (float*)Cout;

#pragma unroll
    for (int i = 0; i < 2; ++i) {
#pragma unroll
        for (int j = 0; j < 4; ++j) {
            int cc = col0 + wn + (j << 4) + r;
#pragma unroll
            for (int reg = 0; reg < 4; ++reg) {
                int rr = row0 + wm + (i << 4) + (qd << 2) + reg;
                float v = acc[i][j][reg];
                if (HAS_BIAS) v += bias[cc];
                if (RELU)     v = fmaxf(v, 0.f);
                if (OUT_MODE == 1)
                    ((unsigned short*)Cout)[(size_t)rr * ldc + cc] = f2bf(v);
                else if (OUT_MODE == 3) {
                    if (cc < QKLD)
                        ((unsigned short*)Cout)[(size_t)rr * QKLD + cc] = f2bf(v);
                    else
                        ((unsigned short*)Cout2)[(size_t)rr * PACKLD + (cc - QKLD)]
                            = f2bf(fmaxf(v, 0.f));
                } else if (OUT_MODE == 5)
                    Cpart[(size_t)rr * ldc + cc] = v;
                else if (OUT_MODE == 6) {
                    if (rr < ROWS) {
                        int b2 = rr / NTOK, tn = rr % NTOK;
                        if (tn > 0) {
                            int n = tn - 1, kh = n / KW_, kw = n % KW_;
                            int c = cc >> 8, p = (cc >> 4) & 15, q = cc & 15;
                            ((float*)Cout)[((size_t)(b2 * C_ + c) * H_ + kh * 16 + p)
                                           * W_ + kw * 16 + q] = v;
                        }
                    }
                } else
                    ((float*)Cout)[(size_t)rr * ldc + cc] = v;
            }
        }
    }
}

// ---------------------------------------------------------------------------
// Fused attention: replaces tqk + attn_pgq + attn_pv.
// One block per (b,h): grid 192, 512 threads (8 waves), 128,000 B LDS.
// Per chunk: S = Qc @ Ks^T (MFMA) -> softmax (beta in exp, m>=NTOK masked)
// -> Pb/PTb -> Gq = Pb @ Kt^T stored to pack[3072..], Gk += PTb @ Qtc^T
// accumulated in registers (7 statically-indexed floatx4), stored at end to
// pack[3840..]. P/PT/kT/qT never touch global memory.
__global__ __launch_bounds__(512) void attn_fused_kernel(
    const unsigned short* __restrict__ qk,   // bf16 [MPAD][1536]
    unsigned short* __restrict__ pack)       // bf16 [MPAD][4608]
{
    __shared__ alignas(16) unsigned short Ks[208 * 72];
    __shared__ alignas(16) unsigned short Kt[64 * 232];
    __shared__ alignas(16) unsigned short Qc[32 * 72];
    __shared__ alignas(16) unsigned short Qtc[64 * 40];
    __shared__ alignas(16) unsigned short Pb[32 * 232];
    __shared__ alignas(16) unsigned short PTb[208 * 40];
    __shared__ alignas(16) float Pm[32 * 212];

    const int bh = blockIdx.x;
    const int h = bh % HEADS_, b = bh / HEADS_;
    const int t = threadIdx.x;
    const int lane = t & 63, wave = t >> 6;
    const int ln15 = lane & 15, quad = lane >> 4;
    const size_t rowbase = (size_t)(b * NTOK) * QKLD;
    const int hoff = h * 64;

    // ---- phase 0: load K_h (zero-padded to 208 rows), zero Pb/PTb ----
    for (int idx = t; idx < 208 * 8; idx += 512) {
        int m = idx >> 3, c8 = idx & 7;
        uint4 v = (uint4){0, 0, 0, 0};
        if (m < NTOK)
            v = *(const uint4*)&qk[rowbase + (size_t)m * QKLD + 768 + hoff + c8 * 8];
        *(uint4*)&Ks[m * 72 + c8 * 8] = v;
    }
    for (int idx = t; idx < (32 * 232) / 8; idx += 512)
        *(uint4*)&Pb[idx * 8] = (uint4){0, 0, 0, 0};
    for (int idx = t; idx < (208 * 40) / 8; idx += 512)
        *(uint4*)&PTb[idx * 8] = (uint4){0, 0, 0, 0};
    __syncthreads();

    // ---- build Kt[y][m] = Ks[m][y]  (m 0..223, zeros past 207) ----
    for (int idx = t; idx < 64 * 112; idx += 512) {
        int y = idx / 112, mp = idx % 112;
        int m0 = 2 * mp;
        unsigned lo = (m0     < 208) ? Ks[(m0    ) * 72 + y] : 0u;
        unsigned hi = (m0 + 1 < 208) ? Ks[(m0 + 1) * 72 + y] : 0u;
        *(unsigned*)&Kt[y * 232 + m0] = lo | (hi << 16);
    }
    __syncthreads();

    // ---- Gk accumulators: 52 (mt,yt) tiles over 8 waves, static index ----
    floatx4 gk[7];
#pragma unroll
    for (int i = 0; i < 7; ++i) gk[i] = (floatx4){0.f, 0.f, 0.f, 0.f};

    for (int nc = 0; nc < 7; ++nc) {
        const int n0 = nc * 32;
        const int csz = (NTOK - n0 < 32) ? (NTOK - n0) : 32;

        // -- load Q chunk (rows >= csz zeroed) --
        for (int idx = t; idx < 32 * 8; idx += 512) {
            int nn = idx >> 3, c8 = idx & 7;
            uint4 v = (uint4){0, 0, 0, 0};
            if (nn < csz)
                v = *(const uint4*)&qk[rowbase + (size_t)(n0 + nn) * QKLD + hoff + c8 * 8];
            *(uint4*)&Qc[nn * 72 + c8 * 8] = v;
        }
        __syncthreads();   // bar1: Qc ready; prev-iter Gq/Gk done (Qtc safe)

        // -- build Qtc[y][nn] = Qc[nn][y]  (cols >= csz zero via Qc pad) --
        for (int idx = t; idx < 64 * 16; idx += 512) {
            int y = idx >> 4, np = idx & 15;
            unsigned lo = Qc[(2 * np    ) * 72 + y];
            unsigned hi = Qc[(2 * np + 1) * 72 + y];
            *(unsigned*)&Qtc[y * 40 + 2 * np] = lo | (hi << 16);
        }

        // -- S = Qc @ Ks^T  (waves split the 13 m-tiles) --
        {
            short8 aq[2][2];
#pragma unroll
            for (int nt = 0; nt < 2; ++nt)
#pragma unroll
                for (int kb = 0; kb < 2; ++kb)
                    aq[nt][kb] = *(const short8*)
                        &Qc[(nt * 16 + ln15) * 72 + kb * 32 + quad * 8];

            for (int mt = wave; mt < 13; mt += 8) {
                short8 b0 = *(const short8*)&Ks[(mt * 16 + ln15) * 72 + quad * 8];
                short8 b1 = *(const short8*)&Ks[(mt * 16 + ln15) * 72 + 32 + quad * 8];
                floatx4 s0 = (floatx4){0.f, 0.f, 0.f, 0.f};
                floatx4 s1 = (floatx4){0.f, 0.f, 0.f, 0.f};
                s0 = __builtin_amdgcn_mfma_f32_16x16x32_bf16(aq[0][0], b0, s0, 0, 0, 0);
                s0 = __builtin_amdgcn_mfma_f32_16x16x32_bf16(aq[0][1], b1, s0, 0, 0, 0);
                s1 = __builtin_amdgcn_mfma_f32_16x16x32_bf16(aq[1][0], b0, s1, 0, 0, 0);
                s1 = __builtin_amdgcn_mfma_f32_16x16x32_bf16(aq[1][1], b1, s1, 0, 0, 0);
#pragma unroll
                for (int reg = 0; reg < 4; ++reg) {
                    Pm[(quad * 4 + reg) * 212 + mt * 16 + ln15]      = s0[reg];
                    Pm[(16 + quad * 4 + reg) * 212 + mt * 16 + ln15] = s1[reg];
                }
            }
        }
        __syncthreads();   // bar2: Pm ready

        // -- softmax rows (beta inside exp); emit Pb (n-major) + PTb (m-major)
        for (int nn = wave; nn < csz; nn += 8) {
            float v0 = Pm[nn * 212 + lane];
            float v1 = (lane +  64 < NTOK) ? Pm[nn * 212 + lane +  64] : -1e30f;
            float v2 = (lane + 128 < NTOK) ? Pm[nn * 212 + lane + 128] : -1e30f;
            float v3 = (lane + 192 < NTOK) ? Pm[nn * 212 + lane + 192] : -1e30f;
            float mx = fmaxf(fmaxf(v0, v1), fmaxf(v2, v3));
#pragma unroll
            for (int o = 32; o > 0; o >>= 1) mx = fmaxf(mx, __shfl_xor(mx, o, 64));
            float e0 = __expf((v0 - mx) * BETA_);
            float e1 = (lane +  64 < NTOK) ? __expf((v1 - mx) * BETA_) : 0.f;
            float e2 = (lane + 128 < NTOK) ? __expf((v2 - mx) * BETA_) : 0.f;
            float e3 = (lane + 192 < NTOK) ? __expf((v3 - mx) * BETA_) : 0.f;
            float s = e0 + e1 + e2 + e3;
#pragma unroll
            for (int o = 32; o > 0; o >>= 1) s += __shfl_xor(s, o, 64);
            float inv = 1.0f / s;
            {
                unsigned short p = f2bf(e0 * inv);
                Pb[nn * 232 + lane] = p;
                PTb[lane * 40 + nn] = p;
            }
            {
                unsigned short p = f2bf(e1 * inv);
                Pb[nn * 232 + lane + 64] = p;
                PTb[(lane + 64) * 40 + nn] = p;
            }
            {
                unsigned short p = f2bf(e2 * inv);
                Pb[nn * 232 + lane + 128] = p;
                PTb[(lane + 128) * 40 + nn] = p;
            }
            if (lane + 192 < NTOK) {
                unsigned short p = f2bf(e3 * inv);
                Pb[nn * 232 + lane + 192] = p;
                PTb[(lane + 192) * 40 + nn] = p;
            }
        }
        __syncthreads();   // bar3: Pb/PTb ready

        // -- Gq = Pb @ Kt^T : 8 output tiles, one per wave; store to pack --
        {
            const int nt = wave >> 2, yt = wave & 3;
            floatx4 gq = (floatx4){0.f, 0.f, 0.f, 0.f};
#pragma unroll
            for (int ks = 0; ks < 7; ++ks) {
                short8 a  = *(const short8*)&Pb[(nt * 16 + ln15) * 232 + ks * 32 + quad * 8];
                short8 bk = *(const short8*)&Kt[(yt * 16 + ln15) * 232 + ks * 32 + quad * 8];
                gq = __builtin_amdgcn_mfma_f32_16x16x32_bf16(a, bk, gq, 0, 0, 0);
            }
#pragma unroll
            for (int reg = 0; reg < 4; ++reg) {
                int row = nt * 16 + quad * 4 + reg;
                if (row < csz)
                    pack[(size_t)(b * NTOK + n0 + row) * PACKLD
                         + 3072 + hoff + yt * 16 + ln15] = f2bf(gq[reg]);
            }
        }

        // -- Gk += PTb @ Qtc^T : 52 tiles over 8 waves (static acc index) --
#pragma unroll
        for (int i = 0; i < 7; ++i) {
            int ti = wave + i * 8;
            if (ti < 52) {
                int mt = ti >> 2, yt = ti & 3;
                short8 a  = *(const short8*)&PTb[(mt * 16 + ln15) * 40 + quad * 8];
                short8 bq = *(const short8*)&Qtc[(yt * 16 + ln15) * 40 + quad * 8];
                gk[i] = __builtin_amdgcn_mfma_f32_16x16x32_bf16(a, bq, gk[i], 0, 0, 0);
            }
        }
    }

    // ---- store Gk ----
#pragma unroll
    for (int i = 0; i < 7; ++i) {
        int ti = wave + i * 8;
        if (ti < 52) {
            int mt = ti >> 2, yt = ti & 3;
#pragma unroll
            for (int reg = 0; reg < 4; ++reg) {
                int m = mt * 16 + quad * 4 + reg;
                if (m < NTOK)
                    pack[(size_t)(b * NTOK + m) * PACKLD
                         + 3840 + hoff + yt * 16 + ln15] = f2bf(gk[i][reg]);
            }
        }
    }
}

// ---------------------------------------------------------------------------
// R16: LDS-tiled transposing packers (G2). The old w2pack/t768 read their
// sources column-wise (stride 12KB/3KB scalar loads — fully uncoalesced,
// ~150MB effective setup traffic). 64x64 fp32 tile: coalesced 64-float row
// reads -> LDS [64][65] (pad -> conflict-free) -> coalesced 128B bf16 row
// writes of the transpose.
// w2pack_t: out[n][d], n<768: Wq[h=n>>6][d][y=n&63]; n<1536: Wk likewise;
//           n>=1536: Xi[d][n-1536]. 64-aligned tiles never cross regions.
__global__ __launch_bounds__(256) void w2pack_t_kernel(
    const float* __restrict__ Wq, const float* __restrict__ Wk,
    const float* __restrict__ Xi, unsigned short* __restrict__ out)
{
    __shared__ float S[64][65];
    const int n0 = blockIdx.x << 6;       // 0..4544, region-aligned
    const int d0 = blockIdx.y << 6;
    const int t = threadIdx.x;
    const int jr = t & 63;                // fast (col on read, col on write)
    const int ir = t >> 6;                // 4 rows per pass

    const float* src; size_t stride;
    if (n0 < 768)       { src = Wq + ((size_t)(n0 >> 6) * D_) * Y_ + (n0 & 63); stride = Y_; }
    else if (n0 < 1536) { int e = n0 - 768;
                          src = Wk + ((size_t)(e >> 6) * D_) * Y_ + (e & 63);   stride = Y_; }
    else                { src = Xi + (n0 - 1536);                               stride = MHID; }

#pragma unroll
    for (int p = 0; p < 16; ++p) {
        int i = (p << 2) + ir;            // source row (d-offset)
        S[i][jr] = src[(size_t)(d0 + i) * stride + jr];
    }
    __syncthreads();
#pragma unroll
    for (int p = 0; p < 16; ++p) {
        int i = (p << 2) + ir;            // out row (n-offset)
        out[(size_t)(n0 + i) * D_ + d0 + jr] = f2bf(S[jr][i]);
    }
}

// t768_t: out[n][k] = bf16(in[k][n]) — 768x768 transpose, same tile scheme.
__global__ __launch_bounds__(256) void t768_t_kernel(
    const float* __restrict__ in, unsigned short* __restrict__ out)
{
    __shared__ float S[64][65];
    const int n0 = blockIdx.x << 6, k0 = blockIdx.y << 6;
    const int t = threadIdx.x;
    const int jr = t & 63, ir = t >> 6;
#pragma unroll
    for (int p = 0; p < 16; ++p) {
        int i = (p << 2) + ir;            // source row (k-offset)
        S[i][jr] = in[(size_t)(k0 + i) * D_ + n0 + jr];
    }
    __syncthreads();
#pragma unroll
    for (int p = 0; p < 16; ++p) {
        int i = (p << 2) + ir;            // out row (n-offset)
        out[(size_t)(n0 + i) * D_ + k0 + jr] = f2bf(S[jr][i]);
    }
}

__global__ __launch_bounds__(256) void bpack_kernel(const float* __restrict__ Xi,
                                                    const float* __restrict__ Wq,
                                                    const float* __restrict__ Wk,
                                                    unsigned short* __restrict__ out)
{
    int idx = blockIdx.x * 256 + threadIdx.x;          // d*4608 + c
    int c = idx % PACKLD, d = idx / PACKLD;
    float v;
    if (c < 3072)       v = Xi[(size_t)d * MHID + c];
    else if (c < 3840)  { int e = c - 3072; v = Wq[((size_t)(e >> 6) * D_ + d) * Y_ + (e & 63)]; }
    else                { int e = c - 3840; v = Wk[((size_t)(e >> 6) * D_ + d) * Y_ + (e & 63)]; }
    out[idx] = f2bf(v);
}

// ---------------------------------------------------------------------------
__global__ void mask_flags_kernel(const int* __restrict__ mask, int* __restrict__ flags)
{
    int b = threadIdx.x;
    if (b >= B_) return;
    const int* mb = mask + b * NPATCH;
    int* fb = flags + b * NPATCH;
    int cnt = 0;
    for (int n = 0; n < NPATCH; ++n) {
        int mv = mb[n];
        fb[n] = (mv == 1 && cnt < NMASK) ? 1 : 0;
        cnt += (mv == 1);
    }
    if (cnt < NMASK) fb[0] = 1;
}

__global__ __launch_bounds__(256) void patchify_kernel(const float* __restrict__ img,
                                                       unsigned short* __restrict__ patch)
{
    int idx = blockIdx.x * 256 + threadIdx.x;          // row*768 + e
    int e = idx % PELEMS, row = idx / PELEMS;
    int b = row / NPATCH, n = row % NPATCH;
    int kh = n / KW_, kw = n % KW_;
    int c = e >> 8, p = (e >> 4) & 15, q2 = e & 15;
    patch[idx] = f2bf(img[(((size_t)b * C_ + c) * H_ + kh * 16 + p) * W_ + kw * 16 + q2]);
}

__global__ __launch_bounds__(256) void build_x_kernel(const float* __restrict__ tok,
                                                      const int* __restrict__ flags,
                                                      const float* __restrict__ cls,
                                                      const float* __restrict__ mtok,
                                                      const float* __restrict__ pos,
                                                      float* __restrict__ x)
{
    int row = blockIdx.x;
    int b = row / NTOK, rr = row % NTOK;
    int tid = threadIdx.x;
#pragma unroll
    for (int i = 0; i < 3; ++i) {
        int d = tid + (i << 8);
        float v;
        if (rr == 0) v = cls[d];
        else {
            int n = rr - 1;
            v = flags[b * NPATCH + n] ? mtok[d]
                                      : tok[((size_t)b * NPATCH + n) * D_ + d];
        }
        x[(size_t)row * D_ + d] = v + pos[(size_t)rr * D_ + d];
    }
}

// ---------------------------------------------------------------------------
// Vectorized layernorm (R13): 192 active lanes x float4 (16B/lane).
__global__ __launch_bounds__(256) void lnorm_kernel(const float* __restrict__ x,
                                                    unsigned short* __restrict__ g,
                                                    const float* __restrict__ gamma,
                                                    const float* __restrict__ delta)
{
    int row = blockIdx.x, tid = threadIdx.x;
    const float* xr = x + (size_t)row * D_;
    const bool act = tid < 192;
    float4 v = act ? *(const float4*)&xr[tid * 4]
                   : make_float4(0.f, 0.f, 0.f, 0.f);

    __shared__ float red[256];
    red[tid] = v.x + v.y + v.z + v.w;
    __syncthreads();
    for (int off = 128; off > 0; off >>= 1) {
        if (tid < off) red[tid] += red[tid + off];
        __syncthreads();
    }
    float mean = red[0] * (1.0f / D_);
    __syncthreads();
    float a0 = v.x - mean, a1 = v.y - mean, a2 = v.z - mean, a3 = v.w - mean;
    red[tid] = act ? (a0 * a0 + a1 * a1 + a2 * a2 + a3 * a3) : 0.f;
    __syncthreads();
    for (int off = 128; off > 0; off >>= 1) {
        if (tid < off) red[tid] += red[tid + off];
        __syncthreads();
    }
    float var = red[0] * (1.0f / D_);
    float inv = gamma[0] / sqrtf(var + EPS_);
    if (act) {
        float4 dl = *(const float4*)&delta[tid * 4];
        ushort4 o;
        o.x = f2bf(a0 * inv + dl.x);
        o.y = f2bf(a1 * inv + dl.y);
        o.z = f2bf(a2 * inv + dl.z);
        o.w = f2bf(a3 * inv + dl.w);
        *(ushort4*)&g[(size_t)row * D_ + tid * 4] = o;
    }
}

// ---------------------------------------------------------------------------
// Fused split-K reduce + x-update + layernorm (R8, vectorized R13).
__global__ __launch_bounds__(256) void upd_lnorm_kernel(
    float* __restrict__ x, const float* __restrict__ part,
    unsigned short* __restrict__ g,
    const float* __restrict__ gamma, const float* __restrict__ delta)
{
    const int row = blockIdx.x, tid = threadIdx.x;
    float* xr = x + (size_t)row * D_;
    const float* pr = part + (size_t)row * D_;
    const size_t zs = (size_t)MPAD * D_;
    const bool act = tid < 192;

    float4 v = make_float4(0.f, 0.f, 0.f, 0.f);
    if (act) {
        const int d = tid * 4;
        float4 p0 = *(const float4*)&pr[d];
        float4 p1 = *(const float4*)&pr[zs + d];
        float4 p2 = *(const float4*)&pr[2 * zs + d];
        float4 p3 = *(const float4*)&pr[3 * zs + d];
        float4 xv = *(const float4*)&xr[d];
        v.x = xv.x + ALPHA_ * (p0.x + p1.x + p2.x + p3.x);
        v.y = xv.y + ALPHA_ * (p0.y + p1.y + p2.y + p3.y);
        v.z = xv.z + ALPHA_ * (p0.z + p1.z + p2.z + p3.z);
        v.w = xv.w + ALPHA_ * (p0.w + p1.w + p2.w + p3.w);
        *(float4*)&xr[d] = v;
    }

    __shared__ float red[256];
    red[tid] = v.x + v.y + v.z + v.w;
    __syncthreads();
    for (int off = 128; off > 0; off >>= 1) {
        if (tid < off) red[tid] += red[tid + off];
        __syncthreads();
    }
    float mean = red[0] * (1.0f / D_);
    __syncthreads();
    float a0 = v.x - mean, a1 = v.y - mean, a2 = v.z - mean, a3 = v.w - mean;
    red[tid] = act ? (a0 * a0 + a1 * a1 + a2 * a2 + a3 * a3) : 0.f;
    __syncthreads();
    for (int off = 128; off > 0; off >>= 1) {
        if (tid < off) red[tid] += red[tid + off];
        __syncthreads();
    }
    float var = red[0] * (1.0f / D_);
    float inv = gamma[0] / sqrtf(var + EPS_);
    if (act) {
        float4 dl = *(const float4*)&delta[tid * 4];
        ushort4 o;
        o.x = f2bf(a0 * inv + dl.x);
        o.y = f2bf(a1 * inv + dl.y);
        o.z = f2bf(a2 * inv + dl.z);
        o.w = f2bf(a3 * inv + dl.w);
        *(ushort4*)&g[(size_t)row * D_ + tid * 4] = o;
    }
}

// ---------------------------------------------------------------------------
extern "C" void kernel_launch(void* const* d_in, const int* in_sizes, int n_in,
                              void* d_out, int out_size, void* d_ws, size_t ws_size,
                              hipStream_t stream)
{
    const float* img   = (const float*)d_in[0];
    const int*   mask  = (const int*)d_in[1];
    const float* enc_W = (const float*)d_in[2];
    const float* enc_b = (const float*)d_in[3];
    const float* dec_W = (const float*)d_in[4];
    const float* dec_b = (const float*)d_in[5];
    const float* cls   = (const float*)d_in[6];
    const float* mtok  = (const float*)d_in[7];
    const float* pos   = (const float*)d_in[8];
    const float* Wq    = (const float*)d_in[9];
    const float* Wk    = (const float*)d_in[10];
    const float* Xi    = (const float*)d_in[11];
    const float* gamma = (const float*)d_in[12];
    const float* delta = (const float*)d_in[13];
    float* out = (float*)d_out;

    float* ws = (float*)d_ws;
    size_t off = 0;
    auto alloc = [&](size_t nfloats) {
        off = (off + 63) & ~(size_t)63;
        float* p = ws + off; off += nfloats; return p;
    };
    float*          x    = alloc((size_t)MPAD * D_);                  // fp32
    unsigned short* g    = (unsigned short*)alloc((size_t)MPAD * D_ / 2);
    unsigned short* qkg  = (unsigned short*)alloc((size_t)MPAD * QKLD / 2);
    unsigned short* pack = (unsigned short*)alloc((size_t)MPAD * PACKLD / 2);
    float*          part = alloc((size_t)KSPLIT * MPAD * D_);         // fp32 partials
    unsigned short* W2   = (unsigned short*)alloc((size_t)W2LD * D_ / 2);
    unsigned short* Bpk  = (unsigned short*)alloc((size_t)D_ * PACKLD / 2);
    unsigned short* decT = (unsigned short*)alloc((size_t)D_ * D_ / 2);
    unsigned short* encT = (unsigned short*)alloc((size_t)D_ * D_ / 2);
    int*            flags = (int*)alloc(B_ * NPATCH);
    // setup-phase overlays inside pack (dead until first hid GEMM)
    unsigned short* patch = pack;                                // MPAD x 768 bf16
    float*          tok   = (float*)(pack + (size_t)MPAD * D_);  // MPAD x 768 fp32

    const dim3 blk(256);

    // ---- one-time packs (R16: LDS-tiled transposes) ----
    w2pack_t_kernel<<<dim3(W2LD / 64, D_ / 64), blk, 0, stream>>>(Wq, Wk, Xi, W2);
    bpack_kernel<<<dim3(D_ * PACKLD / 256), blk, 0, stream>>>(Xi, Wq, Wk, Bpk);
    t768_t_kernel<<<dim3(D_ / 64, D_ / 64), blk, 0, stream>>>(dec_W, decT);
    t768_t_kernel<<<dim3(D_ / 64, D_ / 64), blk, 0, stream>>>(enc_W, encT);
    mask_flags_kernel<<<dim3(1), dim3(64), 0, stream>>>(mask, flags);

    // ---- encode + build x ----
    patchify_kernel<<<dim3(B_ * NPATCH * PELEMS / 256), blk, 0, stream>>>(img, patch);
    mfma_gemm<0, false, true><<<dim3(D_ / 128, MPAD / 64), blk, 0, stream>>>(
        patch, PELEMS, encT, PELEMS, tok, D_, nullptr, enc_b, PELEMS);
    build_x_kernel<<<dim3(ROWS), blk, 0, stream>>>(tok, flags, cls, mtok, pos, x);

    // ---- energy-descent loop ----
    lnorm_kernel<<<dim3(ROWS), blk, 0, stream>>>(x, g, gamma, delta);
    for (int step = 0; step < NSTEPS; ++step) {
        // [qk | hid] = g @ [Wq|Wk|Xi]  (split epilogue, 64x128 tile)
        mfma_gemm<3, false, false><<<dim3(W2LD / 128, MPAD / 64), blk, 0, stream>>>(
            g, D_, W2, D_, qkg, QKLD, pack, nullptr, D_);
        // fused attention: S+softmax+Gq+Gk, all intermediates in LDS
        attn_fused_kernel<<<dim3(B_ * HEADS_), dim3(512), 0, stream>>>(qkg, pack);
        // grad partials: [hid|Gq|Gk] @ [Xi|Wq|Wk]^T  (split-K x4, plain stores)
        mfma_gemm<5, false, false><<<dim3(D_ / 128, MPAD / 64, KSPLIT), blk, 0, stream>>>(
            pack, PACKLD, Bpk, PACKLD, part, D_, nullptr, nullptr, PACKLD / KSPLIT);
        // x += ALPHA*sum(partials); g = lnorm(x)
        upd_lnorm_kernel<<<dim3(ROWS), blk, 0, stream>>>(x, part, g, gamma, delta);
    }

    // ---- decode straight to out (fused unpatchify, mode-6) ----
    mfma_gemm<6, false, true><<<dim3(D_ / 128, MPAD / 64), blk, 0, stream>>>(
        g, D_, decT, D_, out, 0, nullptr, dec_b, D_);
}

// Round 19
// 1705.337 us; speedup vs baseline: 1.1317x; 1.0510x over previous
//
#include <hip/hip_runtime.h>
#include <math.h>

// ---- problem constants ----
#define C_      3
#define H_      224
#define W_      224
#define KH_     14
#define KW_     14
#define NPATCH  196
#define PELEMS  768
#define D_      768
#define HEADS_  12
#define Y_      64
#define MHID    3072
#define NMASK   100
#define NSTEPS  12
#define ALPHA_  0.1f
#define BETA_   0.125f
#define EPS_    1e-5f
#define B_      16
#define NTOK    197
#define ROWS    (B_*NTOK)   /* 3152 real rows */
#define MPAD    3200        /* 50 * 64 */
#define QKLD    1536        /* fused q|k leading dim */
#define PACKLD  4608        /* hid(3072) | Gq(768) | Gk(768) */
#define W2LD    4608        /* qk(1536) | hid(3072) fused B rows */
#define KSPLIT  4           /* grad GEMM split-K (4608/4=1152=18*64).
                               R8-proven partial-store + fused reduce.
                               R17: partials stored bf16 (inputs already bf16;
                               one extra RNE rounding) — halves the 77MB/step
                               partial round-trip. */

typedef short short8 __attribute__((ext_vector_type(8)));
typedef unsigned short ushort8 __attribute__((ext_vector_type(8)));
typedef float floatx4 __attribute__((ext_vector_type(4)));

__device__ __forceinline__ unsigned short f2bf(float f) {
    union { float f; unsigned u; } v; v.f = f;
    unsigned r = (v.u + 0x7FFFu + ((v.u >> 16) & 1u)) >> 16;
    return (unsigned short)r;
}
__device__ __forceinline__ float bf2f(unsigned short u) {
    union { unsigned u; float f; } v; v.u = ((unsigned)u) << 16;
    return v.f;
}

__device__ __forceinline__ void async_cp16(const void* g, void* l) {
    __builtin_amdgcn_global_load_lds(
        (const __attribute__((address_space(1))) unsigned int*)g,
        (__attribute__((address_space(3))) unsigned int*)l, 16, 0, 0);
}

// ---------------------------------------------------------------------------
// MFMA bf16 NT GEMM: C[M][N] = A(MxK bf16) @ B(NxK bf16)^T.
// 64x128 tile, BK=64/iter, single-buffer 2-barrier loop (R2/R8-proven best).
// OUT_MODE: 0 = fp32 store, 1 = bf16 store,
//           3 = split epilogue: col<1536 -> Cout bf16 (ld QKLD), else relu ->
//               Cout2 bf16 (ld PACKLD, col-1536)
//           5 = split-K partial: koff = blockIdx.z*K, bf16 store to
//               Cout + z*MPAD*D_ (no atomics; reduced in upd_lnorm_kernel)
//           6 = decode: fp32 direct to out[B][C][H][W] (fused unpatchify)
template<int OUT_MODE, bool RELU, bool HAS_BIAS>
__global__ __launch_bounds__(256) void mfma_gemm(
    const unsigned short* __restrict__ A, int lda,
    const unsigned short* __restrict__ B, int ldb,
    void* __restrict__ Cout, int ldc, void* __restrict__ Cout2,
    const float* __restrict__ bias, int K)
{
    __shared__ alignas(16) unsigned short ldsA[2][64 * 32];
    __shared__ alignas(16) unsigned short ldsB[2][128 * 32];

    const int bx = blockIdx.x, by = blockIdx.y;
    const int koff = (OUT_MODE == 5) ? blockIdx.z * K : 0;

    const int t    = threadIdx.x;
    const int wave = t >> 6;
    const int lane = t & 63;
    const int row0 = by << 6;
    const int col0 = bx << 7;
    const int wm = (wave & 1) << 5;
    const int wn = (wave >> 1) << 6;
    const int r  = lane & 15;
    const int qd = lane >> 4;

    const unsigned short* Abase = A + (size_t)row0 * lda + koff;
    const unsigned short* Bbase = B + (size_t)col0 * ldb + koff;

    floatx4 acc[2][4];
#pragma unroll
    for (int i = 0; i < 2; ++i)
#pragma unroll
        for (int j = 0; j < 4; ++j)
            acc[i][j] = (floatx4){0.f, 0.f, 0.f, 0.f};

    const int crow = t >> 2;
    const int coff = (t & 3) << 3;
    for (int k0 = 0; k0 < K; k0 += 64) {
#pragma unroll
        for (int kb = 0; kb < 2; ++kb) {
            const int kk = k0 + kb * 32;
            async_cp16(Abase + (size_t)crow * lda + kk + coff,
                       ldsA[kb] + (wave << 9));
            async_cp16(Bbase + (size_t)crow * ldb + kk + coff,
                       ldsB[kb] + (wave << 9));
            async_cp16(Bbase + (size_t)(64 + crow) * ldb + kk + coff,
                       ldsB[kb] + 2048 + (wave << 9));
        }
        __syncthreads();
#pragma unroll
        for (int kb = 0; kb < 2; ++kb) {
            short8 af[2], bfr[4];
#pragma unroll
            for (int i = 0; i < 2; ++i)
                af[i]  = *(const short8*)&ldsA[kb][(wm + (i << 4) + r) * 32 + (qd << 3)];
#pragma unroll
            for (int j = 0; j < 4; ++j)
                bfr[j] = *(const short8*)&ldsB[kb][(wn + (j << 4) + r) * 32 + (qd << 3)];
#pragma unroll
            for (int i = 0; i < 2; ++i)
#pragma unroll
                for (int j = 0; j < 4; ++j)
                    acc[i][j] = __builtin_amdgcn_mfma_f32_16x16x32_bf16(
                                    af[i], bfr[j], acc[i][j], 0, 0, 0);
        }
        __syncthreads();
    }

    unsigned short* Cpart = (OUT_MODE == 5)
        ? (unsigned short*)Cout + (size_t)blockIdx.z * ((size_t)MPAD * D_) : nullptr;

#pragma unroll
    for (int i = 0; i < 2; ++i) {
#pragma unroll
        for (int j = 0; j < 4; ++j) {
            int cc = col0 + wn + (j << 4) + r;
#pragma unroll
            for (int reg = 0; reg < 4; ++reg) {
                int rr = row0 + wm + (i << 4) + (qd << 2) + reg;
                float v = acc[i][j][reg];
                if (HAS_BIAS) v += bias[cc];
                if (RELU)     v = fmaxf(v, 0.f);
                if (OUT_MODE == 1)
                    ((unsigned short*)Cout)[(size_t)rr * ldc + cc] = f2bf(v);
                else if (OUT_MODE == 3) {
                    if (cc < QKLD)
                        ((unsigned short*)Cout)[(size_t)rr * QKLD + cc] = f2bf(v);
                    else
                        ((unsigned short*)Cout2)[(size_t)rr * PACKLD + (cc - QKLD)]
                            = f2bf(fmaxf(v, 0.f));
                } else if (OUT_MODE == 5)
                    Cpart[(size_t)rr * ldc + cc] = f2bf(v);
                else if (OUT_MODE == 6) {
                    if (rr < ROWS) {
                        int b2 = rr / NTOK, tn = rr % NTOK;
                        if (tn > 0) {
                            int n = tn - 1, kh = n / KW_, kw = n % KW_;
                            int c = cc >> 8, p = (cc >> 4) & 15, q = cc & 15;
                            ((float*)Cout)[((size_t)(b2 * C_ + c) * H_ + kh * 16 + p)
                                           * W_ + kw * 16 + q] = v;
                        }
                    }
                } else
                    ((float*)Cout)[(size_t)rr * ldc + cc] = v;
            }
        }
    }
}

// ---------------------------------------------------------------------------
// Fused attention: replaces tqk + attn_pgq + attn_pv.
// One block per (b,h): grid 192, 512 threads (8 waves), 128,000 B LDS.
// Per chunk: S = Qc @ Ks^T (MFMA) -> softmax (beta in exp, m>=NTOK masked)
// -> Pb/PTb -> Gq = Pb @ Kt^T stored to pack[3072..], Gk += PTb @ Qtc^T
// accumulated in registers (7 statically-indexed floatx4), stored at end to
// pack[3840..]. P/PT/kT/qT never touch global memory.
__global__ __launch_bounds__(512) void attn_fused_kernel(
    const unsigned short* __restrict__ qk,   // bf16 [MPAD][1536]
    unsigned short* __restrict__ pack)       // bf16 [MPAD][4608]
{
    __shared__ alignas(16) unsigned short Ks[208 * 72];
    __shared__ alignas(16) unsigned short Kt[64 * 232];
    __shared__ alignas(16) unsigned short Qc[32 * 72];
    __shared__ alignas(16) unsigned short Qtc[64 * 40];
    __shared__ alignas(16) unsigned short Pb[32 * 232];
    __shared__ alignas(16) unsigned short PTb[208 * 40];
    __shared__ alignas(16) float Pm[32 * 212];

    const int bh = blockIdx.x;
    const int h = bh % HEADS_, b = bh / HEADS_;
    const int t = threadIdx.x;
    const int lane = t & 63, wave = t >> 6;
    const int ln15 = lane & 15, quad = lane >> 4;
    const size_t rowbase = (size_t)(b * NTOK) * QKLD;
    const int hoff = h * 64;

    // ---- phase 0: load K_h (zero-padded to 208 rows), zero Pb/PTb ----
    for (int idx = t; idx < 208 * 8; idx += 512) {
        int m = idx >> 3, c8 = idx & 7;
        uint4 v = (uint4){0, 0, 0, 0};
        if (m < NTOK)
            v = *(const uint4*)&qk[rowbase + (size_t)m * QKLD + 768 + hoff + c8 * 8];
        *(uint4*)&Ks[m * 72 + c8 * 8] = v;
    }
    for (int idx = t; idx < (32 * 232) / 8; idx += 512)
        *(uint4*)&Pb[idx * 8] = (uint4){0, 0, 0, 0};
    for (int idx = t; idx < (208 * 40) / 8; idx += 512)
        *(uint4*)&PTb[idx * 8] = (uint4){0, 0, 0, 0};
    __syncthreads();

    // ---- build Kt[y][m] = Ks[m][y]  (m 0..223, zeros past 207) ----
    for (int idx = t; idx < 64 * 112; idx += 512) {
        int y = idx / 112, mp = idx % 112;
        int m0 = 2 * mp;
        unsigned lo = (m0     < 208) ? Ks[(m0    ) * 72 + y] : 0u;
        unsigned hi = (m0 + 1 < 208) ? Ks[(m0 + 1) * 72 + y] : 0u;
        *(unsigned*)&Kt[y * 232 + m0] = lo | (hi << 16);
    }
    __syncthreads();

    // ---- Gk accumulators: 52 (mt,yt) tiles over 8 waves, static index ----
    floatx4 gk[7];
#pragma unroll
    for (int i = 0; i < 7; ++i) gk[i] = (floatx4){0.f, 0.f, 0.f, 0.f};

    for (int nc = 0; nc < 7; ++nc) {
        const int n0 = nc * 32;
        const int csz = (NTOK - n0 < 32) ? (NTOK - n0) : 32;

        // -- load Q chunk (rows >= csz zeroed) --
        for (int idx = t; idx < 32 * 8; idx += 512) {
            int nn = idx >> 3, c8 = idx & 7;
            uint4 v = (uint4){0, 0, 0, 0};
            if (nn < csz)
                v = *(const uint4*)&qk[rowbase + (size_t)(n0 + nn) * QKLD + hoff + c8 * 8];
            *(uint4*)&Qc[nn * 72 + c8 * 8] = v;
        }
        __syncthreads();   // bar1: Qc ready; prev-iter Gq/Gk done (Qtc safe)

        // -- build Qtc[y][nn] = Qc[nn][y]  (cols >= csz zero via Qc pad) --
        for (int idx = t; idx < 64 * 16; idx += 512) {
            int y = idx >> 4, np = idx & 15;
            unsigned lo = Qc[(2 * np    ) * 72 + y];
            unsigned hi = Qc[(2 * np + 1) * 72 + y];
            *(unsigned*)&Qtc[y * 40 + 2 * np] = lo | (hi << 16);
        }

        // -- S = Qc @ Ks^T  (waves split the 13 m-tiles) --
        {
            short8 aq[2][2];
#pragma unroll
            for (int nt = 0; nt < 2; ++nt)
#pragma unroll
                for (int kb = 0; kb < 2; ++kb)
                    aq[nt][kb] = *(const short8*)
                        &Qc[(nt * 16 + ln15) * 72 + kb * 32 + quad * 8];

            for (int mt = wave; mt < 13; mt += 8) {
                short8 b0 = *(const short8*)&Ks[(mt * 16 + ln15) * 72 + quad * 8];
                short8 b1 = *(const short8*)&Ks[(mt * 16 + ln15) * 72 + 32 + quad * 8];
                floatx4 s0 = (floatx4){0.f, 0.f, 0.f, 0.f};
                floatx4 s1 = (floatx4){0.f, 0.f, 0.f, 0.f};
                s0 = __builtin_amdgcn_mfma_f32_16x16x32_bf16(aq[0][0], b0, s0, 0, 0, 0);
                s0 = __builtin_amdgcn_mfma_f32_16x16x32_bf16(aq[0][1], b1, s0, 0, 0, 0);
                s1 = __builtin_amdgcn_mfma_f32_16x16x32_bf16(aq[1][0], b0, s1, 0, 0, 0);
                s1 = __builtin_amdgcn_mfma_f32_16x16x32_bf16(aq[1][1], b1, s1, 0, 0, 0);
#pragma unroll
                for (int reg = 0; reg < 4; ++reg) {
                    Pm[(quad * 4 + reg) * 212 + mt * 16 + ln15]      = s0[reg];
                    Pm[(16 + quad * 4 + reg) * 212 + mt * 16 + ln15] = s1[reg];
                }
            }
        }
        __syncthreads();   // bar2: Pm ready

        // -- softmax rows (beta inside exp); emit Pb (n-major) + PTb (m-major)
        for (int nn = wave; nn < csz; nn += 8) {
            float v0 = Pm[nn * 212 + lane];
            float v1 = (lane +  64 < NTOK) ? Pm[nn * 212 + lane +  64] : -1e30f;
            float v2 = (lane + 128 < NTOK) ? Pm[nn * 212 + lane + 128] : -1e30f;
            float v3 = (lane + 192 < NTOK) ? Pm[nn * 212 + lane + 192] : -1e30f;
            float mx = fmaxf(fmaxf(v0, v1), fmaxf(v2, v3));
#pragma unroll
            for (int o = 32; o > 0; o >>= 1) mx = fmaxf(mx, __shfl_xor(mx, o, 64));
            float e0 = __expf((v0 - mx) * BETA_);
            float e1 = (lane +  64 < NTOK) ? __expf((v1 - mx) * BETA_) : 0.f;
            float e2 = (lane + 128 < NTOK) ? __expf((v2 - mx) * BETA_) : 0.f;
            float e3 = (lane + 192 < NTOK) ? __expf((v3 - mx) * BETA_) : 0.f;
            float s = e0 + e1 + e2 + e3;
#pragma unroll
            for (int o = 32; o > 0; o >>= 1) s += __shfl_xor(s, o, 64);
            float inv = 1.0f / s;
            {
                unsigned short p = f2bf(e0 * inv);
                Pb[nn * 232 + lane] = p;
                PTb[lane * 40 + nn] = p;
            }
            {
                unsigned short p = f2bf(e1 * inv);
                Pb[nn * 232 + lane + 64] = p;
                PTb[(lane + 64) * 40 + nn] = p;
            }
            {
                unsigned short p = f2bf(e2 * inv);
                Pb[nn * 232 + lane + 128] = p;
                PTb[(lane + 128) * 40 + nn] = p;
            }
            if (lane + 192 < NTOK) {
                unsigned short p = f2bf(e3 * inv);
                Pb[nn * 232 + lane + 192] = p;
                PTb[(lane + 192) * 40 + nn] = p;
            }
        }
        __syncthreads();   // bar3: Pb/PTb ready

        // -- Gq = Pb @ Kt^T : 8 output tiles, one per wave; store to pack --
        {
            const int nt = wave >> 2, yt = wave & 3;
            floatx4 gq = (floatx4){0.f, 0.f, 0.f, 0.f};
#pragma unroll
            for (int ks = 0; ks < 7; ++ks) {
                short8 a  = *(const short8*)&Pb[(nt * 16 + ln15) * 232 + ks * 32 + quad * 8];
                short8 bk = *(const short8*)&Kt[(yt * 16 + ln15) * 232 + ks * 32 + quad * 8];
                gq = __builtin_amdgcn_mfma_f32_16x16x32_bf16(a, bk, gq, 0, 0, 0);
            }
#pragma unroll
            for (int reg = 0; reg < 4; ++reg) {
                int row = nt * 16 + quad * 4 + reg;
                if (row < csz)
                    pack[(size_t)(b * NTOK + n0 + row) * PACKLD
                         + 3072 + hoff + yt * 16 + ln15] = f2bf(gq[reg]);
            }
        }

        // -- Gk += PTb @ Qtc^T : 52 tiles over 8 waves (static acc index) --
#pragma unroll
        for (int i = 0; i < 7; ++i) {
            int ti = wave + i * 8;
            if (ti < 52) {
                int mt = ti >> 2, yt = ti & 3;
                short8 a  = *(const short8*)&PTb[(mt * 16 + ln15) * 40 + quad * 8];
                short8 bq = *(const short8*)&Qtc[(yt * 16 + ln15) * 40 + quad * 8];
                gk[i] = __builtin_amdgcn_mfma_f32_16x16x32_bf16(a, bq, gk[i], 0, 0, 0);
            }
        }
    }

    // ---- store Gk ----
#pragma unroll
    for (int i = 0; i < 7; ++i) {
        int ti = wave + i * 8;
        if (ti < 52) {
            int mt = ti >> 2, yt = ti & 3;
#pragma unroll
            for (int reg = 0; reg < 4; ++reg) {
                int m = mt * 16 + quad * 4 + reg;
                if (m < NTOK)
                    pack[(size_t)(b * NTOK + m) * PACKLD
                         + 3840 + hoff + yt * 16 + ln15] = f2bf(gk[i][reg]);
            }
        }
    }
}

// ---------------------------------------------------------------------------
// R16: LDS-tiled transposing packers (G2). 64x64 fp32 tile: coalesced row
// reads -> LDS [64][65] (pad -> conflict-free) -> coalesced bf16 row writes.
__global__ __launch_bounds__(256) void w2pack_t_kernel(
    const float* __restrict__ Wq, const float* __restrict__ Wk,
    const float* __restrict__ Xi, unsigned short* __restrict__ out)
{
    __shared__ float S[64][65];
    const int n0 = blockIdx.x << 6;       // region-aligned
    const int d0 = blockIdx.y << 6;
    const int t = threadIdx.x;
    const int jr = t & 63;
    const int ir = t >> 6;

    const float* src; size_t stride;
    if (n0 < 768)       { src = Wq + ((size_t)(n0 >> 6) * D_) * Y_ + (n0 & 63); stride = Y_; }
    else if (n0 < 1536) { int e = n0 - 768;
                          src = Wk + ((size_t)(e >> 6) * D_) * Y_ + (e & 63);   stride = Y_; }
    else                { src = Xi + (n0 - 1536);                               stride = MHID; }

#pragma unroll
    for (int p = 0; p < 16; ++p) {
        int i = (p << 2) + ir;
        S[i][jr] = src[(size_t)(d0 + i) * stride + jr];
    }
    __syncthreads();
#pragma unroll
    for (int p = 0; p < 16; ++p) {
        int i = (p << 2) + ir;
        out[(size_t)(n0 + i) * D_ + d0 + jr] = f2bf(S[jr][i]);
    }
}

// t768_t: out[n][k] = bf16(in[k][n]) — 768x768 transpose, same tile scheme.
__global__ __launch_bounds__(256) void t768_t_kernel(
    const float* __restrict__ in, unsigned short* __restrict__ out)
{
    __shared__ float S[64][65];
    const int n0 = blockIdx.x << 6, k0 = blockIdx.y << 6;
    const int t = threadIdx.x;
    const int jr = t & 63, ir = t >> 6;
#pragma unroll
    for (int p = 0; p < 16; ++p) {
        int i = (p << 2) + ir;
        S[i][jr] = in[(size_t)(k0 + i) * D_ + n0 + jr];
    }
    __syncthreads();
#pragma unroll
    for (int p = 0; p < 16; ++p) {
        int i = (p << 2) + ir;
        out[(size_t)(n0 + i) * D_ + k0 + jr] = f2bf(S[jr][i]);
    }
}

__global__ __launch_bounds__(256) void bpack_kernel(const float* __restrict__ Xi,
                                                    const float* __restrict__ Wq,
                                                    const float* __restrict__ Wk,
                                                    unsigned short* __restrict__ out)
{
    int idx = blockIdx.x * 256 + threadIdx.x;          // d*4608 + c
    int c = idx % PACKLD, d = idx / PACKLD;
    float v;
    if (c < 3072)       v = Xi[(size_t)d * MHID + c];
    else if (c < 3840)  { int e = c - 3072; v = Wq[((size_t)(e >> 6) * D_ + d) * Y_ + (e & 63)]; }
    else                { int e = c - 3840; v = Wk[((size_t)(e >> 6) * D_ + d) * Y_ + (e & 63)]; }
    out[idx] = f2bf(v);
}

// ---------------------------------------------------------------------------
__global__ void mask_flags_kernel(const int* __restrict__ mask, int* __restrict__ flags)
{
    int b = threadIdx.x;
    if (b >= B_) return;
    const int* mb = mask + b * NPATCH;
    int* fb = flags + b * NPATCH;
    int cnt = 0;
    for (int n = 0; n < NPATCH; ++n) {
        int mv = mb[n];
        fb[n] = (mv == 1 && cnt < NMASK) ? 1 : 0;
        cnt += (mv == 1);
    }
    if (cnt < NMASK) fb[0] = 1;
}

__global__ __launch_bounds__(256) void patchify_kernel(const float* __restrict__ img,
                                                       unsigned short* __restrict__ patch)
{
    int idx = blockIdx.x * 256 + threadIdx.x;          // row*768 + e
    int e = idx % PELEMS, row = idx / PELEMS;
    int b = row / NPATCH, n = row % NPATCH;
    int kh = n / KW_, kw = n % KW_;
    int c = e >> 8, p = (e >> 4) & 15, q2 = e & 15;
    patch[idx] = f2bf(img[(((size_t)b * C_ + c) * H_ + kh * 16 + p) * W_ + kw * 16 + q2]);
}

__global__ __launch_bounds__(256) void build_x_kernel(const float* __restrict__ tok,
                                                      const int* __restrict__ flags,
                                                      const float* __restrict__ cls,
                                                      const float* __restrict__ mtok,
                                                      const float* __restrict__ pos,
                                                      float* __restrict__ x)
{
    int row = blockIdx.x;
    int b = row / NTOK, rr = row % NTOK;
    int tid = threadIdx.x;
#pragma unroll
    for (int i = 0; i < 3; ++i) {
        int d = tid + (i << 8);
        float v;
        if (rr == 0) v = cls[d];
        else {
            int n = rr - 1;
            v = flags[b * NPATCH + n] ? mtok[d]
                                      : tok[((size_t)b * NPATCH + n) * D_ + d];
        }
        x[(size_t)row * D_ + d] = v + pos[(size_t)rr * D_ + d];
    }
}

// ---------------------------------------------------------------------------
// Vectorized layernorm (R13): 192 active lanes x float4 (16B/lane).
__global__ __launch_bounds__(256) void lnorm_kernel(const float* __restrict__ x,
                                                    unsigned short* __restrict__ g,
                                                    const float* __restrict__ gamma,
                                                    const float* __restrict__ delta)
{
    int row = blockIdx.x, tid = threadIdx.x;
    const float* xr = x + (size_t)row * D_;
    const bool act = tid < 192;
    float4 v = act ? *(const float4*)&xr[tid * 4]
                   : make_float4(0.f, 0.f, 0.f, 0.f);

    __shared__ float red[256];
    red[tid] = v.x + v.y + v.z + v.w;
    __syncthreads();
    for (int off = 128; off > 0; off >>= 1) {
        if (tid < off) red[tid] += red[tid + off];
        __syncthreads();
    }
    float mean = red[0] * (1.0f / D_);
    __syncthreads();
    float a0 = v.x - mean, a1 = v.y - mean, a2 = v.z - mean, a3 = v.w - mean;
    red[tid] = act ? (a0 * a0 + a1 * a1 + a2 * a2 + a3 * a3) : 0.f;
    __syncthreads();
    for (int off = 128; off > 0; off >>= 1) {
        if (tid < off) red[tid] += red[tid + off];
        __syncthreads();
    }
    float var = red[0] * (1.0f / D_);
    float inv = gamma[0] / sqrtf(var + EPS_);
    if (act) {
        float4 dl = *(const float4*)&delta[tid * 4];
        ushort4 o;
        o.x = f2bf(a0 * inv + dl.x);
        o.y = f2bf(a1 * inv + dl.y);
        o.z = f2bf(a2 * inv + dl.z);
        o.w = f2bf(a3 * inv + dl.w);
        *(ushort4*)&g[(size_t)row * D_ + tid * 4] = o;
    }
}

// ---------------------------------------------------------------------------
// Fused split-K reduce + x-update + layernorm (R8, vectorized R13, bf16
// partials R17): x += ALPHA*(p0+p1+p2+p3), then lnorm(x) -> g.
__global__ __launch_bounds__(256) void upd_lnorm_kernel(
    float* __restrict__ x, const unsigned short* __restrict__ part,
    unsigned short* __restrict__ g,
    const float* __restrict__ gamma, const float* __restrict__ delta)
{
    const int row = blockIdx.x, tid = threadIdx.x;
    float* xr = x + (size_t)row * D_;
    const unsigned short* pr = part + (size_t)row * D_;
    const size_t zs = (size_t)MPAD * D_;
    const bool act = tid < 192;

    float4 v = make_float4(0.f, 0.f, 0.f, 0.f);
    if (act) {
        const int d = tid * 4;
        ushort4 q0 = *(const ushort4*)&pr[d];
        ushort4 q1 = *(const ushort4*)&pr[zs + d];
        ushort4 q2 = *(const ushort4*)&pr[2 * zs + d];
        ushort4 q3 = *(const ushort4*)&pr[3 * zs + d];
        float4 xv = *(const float4*)&xr[d];
        v.x = xv.x + ALPHA_ * (bf2f(q0.x) + bf2f(q1.x) + bf2f(q2.x) + bf2f(q3.x));
        v.y = xv.y + ALPHA_ * (bf2f(q0.y) + bf2f(q1.y) + bf2f(q2.y) + bf2f(q3.y));
        v.z = xv.z + ALPHA_ * (bf2f(q0.z) + bf2f(q1.z) + bf2f(q2.z) + bf2f(q3.z));
        v.w = xv.w + ALPHA_ * (bf2f(q0.w) + bf2f(q1.w) + bf2f(q2.w) + bf2f(q3.w));
        *(float4*)&xr[d] = v;
    }

    __shared__ float red[256];
    red[tid] = v.x + v.y + v.z + v.w;
    __syncthreads();
    for (int off = 128; off > 0; off >>= 1) {
        if (tid < off) red[tid] += red[tid + off];
        __syncthreads();
    }
    float mean = red[0] * (1.0f / D_);
    __syncthreads();
    float a0 = v.x - mean, a1 = v.y - mean, a2 = v.z - mean, a3 = v.w - mean;
    red[tid] = act ? (a0 * a0 + a1 * a1 + a2 * a2 + a3 * a3) : 0.f;
    __syncthreads();
    for (int off = 128; off > 0; off >>= 1) {
        if (tid < off) red[tid] += red[tid + off];
        __syncthreads();
    }
    float var = red[0] * (1.0f / D_);
    float inv = gamma[0] / sqrtf(var + EPS_);
    if (act) {
        float4 dl = *(const float4*)&delta[tid * 4];
        ushort4 o;
        o.x = f2bf(a0 * inv + dl.x);
        o.y = f2bf(a1 * inv + dl.y);
        o.z = f2bf(a2 * inv + dl.z);
        o.w = f2bf(a3 * inv + dl.w);
        *(ushort4*)&g[(size_t)row * D_ + tid * 4] = o;
    }
}

// ---------------------------------------------------------------------------
extern "C" void kernel_launch(void* const* d_in, const int* in_sizes, int n_in,
                              void* d_out, int out_size, void* d_ws, size_t ws_size,
                              hipStream_t stream)
{
    const float* img   = (const float*)d_in[0];
    const int*   mask  = (const int*)d_in[1];
    const float* enc_W = (const float*)d_in[2];
    const float* enc_b = (const float*)d_in[3];
    const float* dec_W = (const float*)d_in[4];
    const float* dec_b = (const float*)d_in[5];
    const float* cls   = (const float*)d_in[6];
    const float* mtok  = (const float*)d_in[7];
    const float* pos   = (const float*)d_in[8];
    const float* Wq    = (const float*)d_in[9];
    const float* Wk    = (const float*)d_in[10];
    const float* Xi    = (const float*)d_in[11];
    const float* gamma = (const float*)d_in[12];
    const float* delta = (const float*)d_in[13];
    float* out = (float*)d_out;

    float* ws = (float*)d_ws;
    size_t off = 0;
    auto alloc = [&](size_t nfloats) {
        off = (off + 63) & ~(size_t)63;
        float* p = ws + off; off += nfloats; return p;
    };
    float*          x    = alloc((size_t)MPAD * D_);                  // fp32
    unsigned short* g    = (unsigned short*)alloc((size_t)MPAD * D_ / 2);
    unsigned short* qkg  = (unsigned short*)alloc((size_t)MPAD * QKLD / 2);
    unsigned short* pack = (unsigned short*)alloc((size_t)MPAD * PACKLD / 2);
    unsigned short* part = (unsigned short*)alloc((size_t)KSPLIT * MPAD * D_ / 2); // bf16 partials
    unsigned short* W2   = (unsigned short*)alloc((size_t)W2LD * D_ / 2);
    unsigned short* Bpk  = (unsigned short*)alloc((size_t)D_ * PACKLD / 2);
    unsigned short* decT = (unsigned short*)alloc((size_t)D_ * D_ / 2);
    unsigned short* encT = (unsigned short*)alloc((size_t)D_ * D_ / 2);
    int*            flags = (int*)alloc(B_ * NPATCH);
    // setup-phase overlays inside pack (dead until first hid GEMM)
    unsigned short* patch = pack;                                // MPAD x 768 bf16
    float*          tok   = (float*)(pack + (size_t)MPAD * D_);  // MPAD x 768 fp32

    const dim3 blk(256);

    // ---- one-time packs (R16: LDS-tiled transposes) ----
    w2pack_t_kernel<<<dim3(W2LD / 64, D_ / 64), blk, 0, stream>>>(Wq, Wk, Xi, W2);
    bpack_kernel<<<dim3(D_ * PACKLD / 256), blk, 0, stream>>>(Xi, Wq, Wk, Bpk);
    t768_t_kernel<<<dim3(D_ / 64, D_ / 64), blk, 0, stream>>>(dec_W, decT);
    t768_t_kernel<<<dim3(D_ / 64, D_ / 64), blk, 0, stream>>>(enc_W, encT);
    mask_flags_kernel<<<dim3(1), dim3(64), 0, stream>>>(mask, flags);

    // ---- encode + build x ----
    patchify_kernel<<<dim3(B_ * NPATCH * PELEMS / 256), blk, 0, stream>>>(img, patch);
    mfma_gemm<0, false, true><<<dim3(D_ / 128, MPAD / 64), blk, 0, stream>>>(
        patch, PELEMS, encT, PELEMS, tok, D_, nullptr, enc_b, PELEMS);
    build_x_kernel<<<dim3(ROWS), blk, 0, stream>>>(tok, flags, cls, mtok, pos, x);

    // ---- energy-descent loop ----
    lnorm_kernel<<<dim3(ROWS), blk, 0, stream>>>(x, g, gamma, delta);
    for (int step = 0; step < NSTEPS; ++step) {
        // [qk | hid] = g @ [Wq|Wk|Xi]  (split epilogue, 64x128 tile)
        mfma_gemm<3, false, false><<<dim3(W2LD / 128, MPAD / 64), blk, 0, stream>>>(
            g, D_, W2, D_, qkg, QKLD, pack, nullptr, D_);
        // fused attention: S+softmax+Gq+Gk, all intermediates in LDS
        attn_fused_kernel<<<dim3(B_ * HEADS_), dim3(512), 0, stream>>>(qkg, pack);
        // grad partials: [hid|Gq|Gk] @ [Xi|Wq|Wk]^T  (split-K x4, bf16 stores)
        mfma_gemm<5, false, false><<<dim3(D_ / 128, MPAD / 64, KSPLIT), blk, 0, stream>>>(
            pack, PACKLD, Bpk, PACKLD, part, D_, nullptr, nullptr, PACKLD / KSPLIT);
        // x += ALPHA*sum(partials); g = lnorm(x)
        upd_lnorm_kernel<<<dim3(ROWS), blk, 0, stream>>>(x, part, g, gamma, delta);
    }

    // ---- decode straight to out (fused unpatchify, mode-6) ----
    mfma_gemm<6, false, true><<<dim3(D_ / 128, MPAD / 64), blk, 0, stream>>>(
        g, D_, decT, D_, out, 0, nullptr, dec_b, D_);
}